// Round 5
// baseline (381.010 us; speedup 1.0000x reference)
//
#include <hip/hip_runtime.h>
#include <hip/hip_bf16.h>

typedef unsigned short u16;
typedef __attribute__((ext_vector_type(8))) short short8;   // 8 bf16 (4 VGPRs)
typedef __attribute__((ext_vector_type(4))) float f32x4;

#define NTOK 740
#define NTMP 256
#define NTGT 484
#define DM   512
#define MH   8
#define MROWS 11840   // B*NTOK = 16*740
#define KPAD 768      // keys padded to chunk multiple

__device__ __forceinline__ float b2f(u16 u) {
    union { unsigned int i; float f; } x; x.i = ((unsigned int)u) << 16; return x.f;
}
__device__ __forceinline__ u16 f2b(float f) {
    union { float f; unsigned int i; } x; x.f = f;
    unsigned int r = x.i + 0x7FFFu + ((x.i >> 16) & 1u);   // RNE
    return (u16)(r >> 16);
}
struct alignas(8) us4 { u16 x, y, z, w; };

// -------- weight transpose + bf16 convert: WT[n][k] = W[k][n], 512x512 --------
__global__ __launch_bounds__(256) void transpose512(const float* __restrict__ W,
                                                    u16* __restrict__ WT) {
    __shared__ float t[32][33];
    int bx = blockIdx.x, by = blockIdx.y;
    int tx = threadIdx.x;           // 0..31
    for (int i = threadIdx.y; i < 32; i += 8)
        t[i][tx] = W[(size_t)(by * 32 + i) * 512 + bx * 32 + tx];
    __syncthreads();
    for (int i = threadIdx.y; i < 32; i += 8)
        WT[(size_t)(bx * 32 + i) * 512 + by * 32 + tx] = f2b(t[tx][i]);
}

// ---------------- depthwise 3x3 conv + BN (one branch), f32 in -> bf16 out ----
__global__ __launch_bounds__(256) void conv_bn(const float* __restrict__ x,
                                               const float* __restrict__ cw,
                                               const float* __restrict__ g,
                                               const float* __restrict__ bb,
                                               const float* __restrict__ m,
                                               const float* __restrict__ v,
                                               u16* __restrict__ out) {
    int bn = blockIdx.x;
    int b = bn / NTOK, n = bn % NTOK;
    bool tmp = n < NTMP;
    int L = tmp ? 16 : 22, base = tmp ? 0 : NTMP, p = n - base;
    int ph = p / L, pw = p % L;
    int nb[9]; bool ok[9];
#pragma unroll
    for (int tap = 0; tap < 9; ++tap) {
        int dh = tap / 3 - 1, dw = tap % 3 - 1;
        int h2 = ph + dh, w2 = pw + dw;
        ok[tap] = (h2 >= 0 && h2 < L && w2 >= 0 && w2 < L);
        nb[tap] = ok[tap] ? (b * NTOK + base + h2 * L + w2) : 0;
    }
    for (int c = threadIdx.x; c < DM; c += 256) {
        float acc = 0.f;
#pragma unroll
        for (int tap = 0; tap < 9; ++tap)
            if (ok[tap]) acc = fmaf(cw[c * 9 + tap], x[(size_t)nb[tap] * DM + c], acc);
        float inv = g[c] * rsqrtf(v[c] + 1e-5f);
        out[(size_t)bn * DM + c] = f2b((acc - m[c]) * inv + bb[c]);
    }
}

// ---------------- MFMA GEMM: C[M,512] = A[M,512] @ BT^T + bias ----------------
// XOR-swizzled LDS (16B chunk ^ row&3) -> conflict-free ds_read_b128.
template <typename OT>
__global__ __launch_bounds__(256) void gemm_bias(const u16* __restrict__ A,
                                                 const u16* __restrict__ BT,
                                                 const float* __restrict__ bias,
                                                 OT* __restrict__ C, int M) {
    __shared__ u16 As[128][32];
    __shared__ u16 Bs[128][32];
    const int tid = threadIdx.x;
    const int gm0 = blockIdx.x * 128;
    const int gn0 = blockIdx.y * 128;
    const int lane = tid & 63;
    const int wid = tid >> 6;
    const int wm = (wid >> 1) * 64, wn = (wid & 1) * 64;
    const int lr = lane & 15, lg = lane >> 4;
    const int r = tid >> 2;             // 0..63
    const int sc = tid & 3;             // chunk 0..3
    const int cg = sc * 8;
    f32x4 acc[4][4] = {};

    for (int kt = 0; kt < 16; ++kt) {
        const int k0 = kt * 32;
        __syncthreads();
        for (int rr = r; rr < 128; rr += 64) {
            int gr = gm0 + rr;
            int4 av;
            if (gr < M) av = *(const int4*)(A + (size_t)gr * 512 + k0 + cg);
            else av = int4{0, 0, 0, 0};
            *(int4*)&As[rr][((sc ^ (rr & 3))) * 8] = av;
            int4 bv = *(const int4*)(BT + (size_t)(gn0 + rr) * 512 + k0 + cg);
            *(int4*)&Bs[rr][((sc ^ (rr & 3))) * 8] = bv;
        }
        __syncthreads();
        short8 af[4], bfr[4];
#pragma unroll
        for (int i = 0; i < 4; ++i) {
            af[i]  = *(const short8*)&As[wm + i * 16 + lr][(lg ^ (lr & 3)) * 8];
            bfr[i] = *(const short8*)&Bs[wn + i * 16 + lr][(lg ^ (lr & 3)) * 8];
        }
#pragma unroll
        for (int i = 0; i < 4; ++i)
#pragma unroll
            for (int j = 0; j < 4; ++j)
                acc[i][j] = __builtin_amdgcn_mfma_f32_16x16x32_bf16(af[i], bfr[j], acc[i][j], 0, 0, 0);
    }
    const int orow = lg * 4;
#pragma unroll
    for (int i = 0; i < 4; ++i)
#pragma unroll
        for (int j = 0; j < 4; ++j) {
            const int gc = gn0 + wn + j * 16 + lr;
            const float bv = bias[gc];
#pragma unroll
            for (int rr2 = 0; rr2 < 4; ++rr2) {
                const int gr = gm0 + wm + i * 16 + orow + rr2;
                if (gr < M) {
                    const float val = acc[i][j][rr2] + bv;
                    if constexpr (sizeof(OT) == 2) C[(size_t)gr * 512 + gc] = (OT)f2b(val);
                    else                           C[(size_t)gr * 512 + gc] = (OT)val;
                }
            }
        }
}

// -------- V transpose: vbT[b][h][d][k] = vb[b*740+k][h*64+d], k padded to 768 --------
__global__ __launch_bounds__(256) void transposeV(const u16* __restrict__ vb,
                                                  u16* __restrict__ vbT) {
    __shared__ u16 t[64][72];
    const int b = blockIdx.z, h = blockIdx.y, k0 = blockIdx.x * 64;
    const int tid = threadIdx.x;
    const size_t brow = (size_t)b * NTOK;
#pragma unroll
    for (int pass = 0; pass < 2; ++pass) {
        const int rr = pass * 32 + (tid >> 3);      // key within tile
        const int d8 = (tid & 7) * 8;
        const int key = k0 + rr;
        int4 v;
        if (key < NTOK) v = *(const int4*)(vb + (brow + key) * DM + h * 64 + d8);
        else v = int4{0, 0, 0, 0};
        *(int4*)&t[rr][d8] = v;
    }
    __syncthreads();
    const size_t obase = ((size_t)(b * MH + h) * 64) * KPAD + k0;
#pragma unroll
    for (int pass = 0; pass < 2; ++pass) {
        const int d = pass * 32 + (tid >> 3);       // 0..63
        const int k8 = (tid & 7) * 8;
        us4 o0, o1;
        o0.x = t[k8 + 0][d]; o0.y = t[k8 + 1][d]; o0.z = t[k8 + 2][d]; o0.w = t[k8 + 3][d];
        o1.x = t[k8 + 4][d]; o1.y = t[k8 + 5][d]; o1.z = t[k8 + 6][d]; o1.w = t[k8 + 7][d];
        *(us4*)(vbT + obase + (size_t)d * KPAD + k8) = o0;
        *(us4*)(vbT + obase + (size_t)d * KPAD + k8 + 4) = o1;
    }
}

// -------- bias tables (batch-independent; computed once, L2-resident) --------
// btab[h][q][k] (k padded 768): k<256 -> tt+tg; 256<=k<740 -> rpb_target; else -1e30
__global__ __launch_bounds__(256) void build_bias_t(const float* __restrict__ rpb_t,
                                                    const float* __restrict__ tt,
                                                    const float* __restrict__ tg,
                                                    u16* __restrict__ btab) {
    const int q = blockIdx.x, h = blockIdx.y;
    const int qh = q / 22, qw = q % 22;
    const float tgv = tg[h * NTGT + q];
    for (int k = threadIdx.x; k < KPAD; k += 256) {
        float val;
        if (k < NTMP) val = tt[h * NTMP + k] + tgv;
        else if (k < NTOK) {
            const int kj = k - NTMP, kh = kj / 22, kw = kj % 22;
            val = rpb_t[((qh - kh + 21) * 43 + (qw - kw + 21)) * MH + h];
        } else val = -1e30f;
        btab[((size_t)(h * NTGT + q)) * KPAD + k] = f2b(val);
    }
}
// mtab[q][k], 256x256
__global__ __launch_bounds__(256) void build_bias_m(const float* __restrict__ rpb_m,
                                                    u16* __restrict__ mtab) {
    const int q = blockIdx.x, k = threadIdx.x;
    const int qh = q >> 4, qw = q & 15, kh = k >> 4, kw = k & 15;
    mtab[q * 256 + k] = f2b(rpb_m[(qh - kh + 15) * 31 + (qw - kw + 15)]);
}

// ---------------- MFMA flash-style attention (64-key chunks, swizzled LDS) ----------------
// One block per (b, h, 64-q tile). 4 waves x 16 q-rows.
template <bool TARGET>
__global__ __launch_bounds__(256) void attn_mfma(const u16* __restrict__ qb,
                                                 const u16* __restrict__ kb,
                                                 const u16* __restrict__ vbT,
                                                 const u16* __restrict__ tab,
                                                 u16* __restrict__ attb) {
    constexpr int NK   = TARGET ? NTOK : NTMP;
    constexpr int NCH  = TARGET ? 12 : 4;           // 64-key chunks (768 / 256)
    constexpr int QTOT = TARGET ? NTGT : NTMP;
    constexpr int QOFF = TARGET ? NTMP : 0;
    constexpr int TK   = TARGET ? KPAD : 256;       // tab row length

    __shared__ u16 Ks[2][64][64];    // keys x d (swizzled 16B chunks)
    __shared__ u16 VTs[2][64][64];   // d x keys (swizzled)
    __shared__ u16 Pb[4][16][64];    // per-wave P: q x 64 keys (swizzled)

    const int b = blockIdx.z, h = blockIdx.y;
    const int q0 = blockIdx.x * 64;
    const int tid = threadIdx.x;
    const int w = tid >> 6, lane = tid & 63;
    const int lq = lane & 15, lg = lane >> 4;       // q-col / group
    const size_t brow = (size_t)b * NTOK;

    int qmine = q0 + w * 16 + lq;
    if (qmine > QTOT - 1) qmine = QTOT - 1;
    const u16* trow = tab + (size_t)(TARGET ? (h * NTGT + qmine) : qmine) * TK;

    // Q fragments (B-operand): col=lq, k=lg*8+e
    short8 qf[2];
#pragma unroll
    for (int dc = 0; dc < 2; ++dc)
        qf[dc] = *(const short8*)(qb + (brow + QOFF + qmine) * DM + h * 64 + dc * 32 + lg * 8);

    // staging coordinates: row = tid>>2 (0..63), chunk sc = tid&3 (two passes p)
    const int srow = tid >> 2, sc = tid & 3;
    const size_t vbase = ((size_t)(b * MH + h) * 64) * KPAD;

    float mrun = -1e30f, lrun = 0.f;
    f32x4 acc_o[4] = {};

    // prologue: stage chunk 0
#pragma unroll
    for (int p = 0; p < 2; ++p) {
        const int col = sc * 8 + p * 32, ch = sc + p * 4;
        int4 kv = (srow < NK) ? *(const int4*)(kb + (brow + srow) * DM + h * 64 + col)
                              : int4{0, 0, 0, 0};
        *(int4*)&Ks[0][srow][(ch ^ (srow & 7)) * 8] = kv;
        int4 vv = *(const int4*)(vbT + vbase + (size_t)srow * KPAD + col);
        *(int4*)&VTs[0][srow][(ch ^ (srow & 7)) * 8] = vv;
    }
    __syncthreads();

    for (int kc = 0; kc < NCH; ++kc) {
        const int cur = kc & 1, nxt = cur ^ 1;
        // issue next-chunk global loads early (T14)
        int4 nk[2] = {{0,0,0,0},{0,0,0,0}}, nv[2] = {{0,0,0,0},{0,0,0,0}};
        if (kc + 1 < NCH) {
            const int kbase = (kc + 1) * 64;
#pragma unroll
            for (int p = 0; p < 2; ++p) {
                const int col = sc * 8 + p * 32;
                const int key = kbase + srow;
                if (key < NK) nk[p] = *(const int4*)(kb + (brow + key) * DM + h * 64 + col);
                nv[p] = *(const int4*)(vbT + vbase + (size_t)srow * KPAD + kbase + col);
            }
        }

        // ---- S^T: 4 sub-tiles of 16 keys x 16 q ----
        f32x4 s[4] = {};
#pragma unroll
        for (int sub = 0; sub < 4; ++sub)
#pragma unroll
            for (int dc = 0; dc < 2; ++dc) {
                short8 ak = *(const short8*)&Ks[cur][sub * 16 + lq][((dc * 4 + lg) ^ (lq & 7)) * 8];
                s[sub] = __builtin_amdgcn_mfma_f32_16x16x32_bf16(ak, qf[dc], s[sub], 0, 0, 0);
            }

        // ---- scale + table bias ----
        float sv[4][4];
#pragma unroll
        for (int sub = 0; sub < 4; ++sub) {
            const us4 bb = *(const us4*)(trow + kc * 64 + sub * 16 + lg * 4);
            sv[sub][0] = fmaf(s[sub][0], 0.125f, b2f(bb.x));
            sv[sub][1] = fmaf(s[sub][1], 0.125f, b2f(bb.y));
            sv[sub][2] = fmaf(s[sub][2], 0.125f, b2f(bb.z));
            sv[sub][3] = fmaf(s[sub][3], 0.125f, b2f(bb.w));
        }

        // ---- online softmax (stats per q at lane&15) ----
        float cm = sv[0][0];
#pragma unroll
        for (int sub = 0; sub < 4; ++sub)
#pragma unroll
            for (int r2 = 0; r2 < 4; ++r2) cm = fmaxf(cm, sv[sub][r2]);
        cm = fmaxf(cm, __shfl_xor(cm, 16));
        cm = fmaxf(cm, __shfl_xor(cm, 32));
        const float mnew = fmaxf(mrun, cm);
        const float alpha = __expf(mrun - mnew);
        float psum = 0.f;
#pragma unroll
        for (int sub = 0; sub < 4; ++sub) {
            float p0 = __expf(sv[sub][0] - mnew), p1 = __expf(sv[sub][1] - mnew);
            float p2 = __expf(sv[sub][2] - mnew), p3 = __expf(sv[sub][3] - mnew);
            psum += (p0 + p1) + (p2 + p3);
            us4 pw;
            pw.x = f2b(p0); pw.y = f2b(p1); pw.z = f2b(p2); pw.w = f2b(p3);
            const int ch = sub * 2 + (lg >> 1);
            *(us4*)&Pb[w][lq][(ch ^ (lq & 7)) * 8 + (lg & 1) * 4] = pw;
        }
        psum += __shfl_xor(psum, 16);
        psum += __shfl_xor(psum, 32);
        lrun = lrun * alpha + psum;
        mrun = mnew;

        // rescale O (O rows q = lg*4+r -> alpha from lane q)
        float af_[4];
#pragma unroll
        for (int r2 = 0; r2 < 4; ++r2) af_[r2] = __shfl(alpha, lg * 4 + r2);
#pragma unroll
        for (int t = 0; t < 4; ++t)
#pragma unroll
            for (int r2 = 0; r2 < 4; ++r2) acc_o[t][r2] *= af_[r2];

        // P visible within wave
        asm volatile("s_waitcnt lgkmcnt(0)" ::: "memory");

        // ---- PV: O[q][d] += P[q][64k] * V[64k][16d] ----
#pragma unroll
        for (int ks = 0; ks < 2; ++ks) {
            short8 pf = *(const short8*)&Pb[w][lq][((ks * 4 + lg) ^ (lq & 7)) * 8];
#pragma unroll
            for (int t = 0; t < 4; ++t) {
                short8 vf = *(const short8*)&VTs[cur][t * 16 + lq][((ks * 4 + lg) ^ (lq & 7)) * 8];
                acc_o[t] = __builtin_amdgcn_mfma_f32_16x16x32_bf16(pf, vf, acc_o[t], 0, 0, 0);
            }
        }

        // stage next chunk
        if (kc + 1 < NCH) {
#pragma unroll
            for (int p = 0; p < 2; ++p) {
                const int ch = sc + p * 4;
                *(int4*)&Ks[nxt][srow][(ch ^ (srow & 7)) * 8] = nk[p];
                *(int4*)&VTs[nxt][srow][(ch ^ (srow & 7)) * 8] = nv[p];
            }
        }
        __syncthreads();
    }

    // epilogue: normalize, store (O rows q=lg*4+r, cols d=t*16+lq)
    float linv[4];
#pragma unroll
    for (int r2 = 0; r2 < 4; ++r2) linv[r2] = 1.f / __shfl(lrun, lg * 4 + r2);
#pragma unroll
    for (int t = 0; t < 4; ++t)
#pragma unroll
        for (int r2 = 0; r2 < 4; ++r2) {
            const int qrow = q0 + w * 16 + lg * 4 + r2;
            if (qrow < QTOT)
                attb[(brow + QOFF + qrow) * DM + h * 64 + t * 16 + lq] = f2b(acc_o[t][r2] * linv[r2]);
        }
}

// ---------------- launch ----------------
extern "C" void kernel_launch(void* const* d_in, const int* in_sizes, int n_in,
                              void* d_out, int out_size, void* d_ws, size_t ws_size,
                              hipStream_t stream) {
    const float* x = (const float*)d_in[0];
    const float* convw[3] = {(const float*)d_in[1], (const float*)d_in[6], (const float*)d_in[11]};
    const float* bng[3]   = {(const float*)d_in[2], (const float*)d_in[7], (const float*)d_in[12]};
    const float* bnb[3]   = {(const float*)d_in[3], (const float*)d_in[8], (const float*)d_in[13]};
    const float* bnm[3]   = {(const float*)d_in[4], (const float*)d_in[9], (const float*)d_in[14]};
    const float* bnv[3]   = {(const float*)d_in[5], (const float*)d_in[10], (const float*)d_in[15]};
    const float* w[4]     = {(const float*)d_in[16], (const float*)d_in[18], (const float*)d_in[20], (const float*)d_in[22]};
    const float* bias[4]  = {(const float*)d_in[17], (const float*)d_in[19], (const float*)d_in[21], (const float*)d_in[23]};
    const float* rpb_t = (const float*)d_in[24];
    const float* rpb_m = (const float*)d_in[25];
    const float* tt    = (const float*)d_in[26];
    const float* tg    = (const float*)d_in[27];

    char* ws = (char*)d_ws;
    u16* wT[4];
    for (int i = 0; i < 4; ++i) wT[i] = (u16*)(ws + (size_t)i * 524288);
    const size_t SEQ = (size_t)MROWS * DM * 2;   // 12,124,160 B
    u16* cb  = (u16*)(ws + 2097152);
    u16* qb  = (u16*)(ws + 2097152 + SEQ);
    u16* kb  = (u16*)(ws + 2097152 + 2 * SEQ);
    u16* vb  = (u16*)(ws + 2097152 + 3 * SEQ);
    u16* vbT = (u16*)(ws + 2097152 + 4 * SEQ);                    // 12.58 MB
    u16* btab = (u16*)(ws + 2097152 + 4 * SEQ + 12582912);        // 5.95 MB
    u16* mtab = (u16*)(ws + 2097152 + 4 * SEQ + 12582912 + 5947392);  // 131 KB
    u16* attb = cb;   // cb dead after the 3rd GEMM; reuse for attention output

    for (int i = 0; i < 4; ++i)
        transpose512<<<dim3(16, 16), dim3(32, 8), 0, stream>>>(w[i], wT[i]);
    build_bias_t<<<dim3(NTGT, MH), 256, 0, stream>>>(rpb_t, tt, tg, btab);
    build_bias_m<<<256, 256, 0, stream>>>(rpb_m, mtab);

    u16* qkv[3] = {qb, kb, vb};
    for (int br = 0; br < 3; ++br) {
        conv_bn<<<MROWS, 256, 0, stream>>>(x, convw[br], bng[br], bnb[br], bnm[br], bnv[br], cb);
        gemm_bias<u16><<<dim3(93, 4), 256, 0, stream>>>(cb, wT[br], bias[br], qkv[br], MROWS);
    }
    transposeV<<<dim3(12, 8, 16), 256, 0, stream>>>(vb, vbT);
    attn_mfma<true><<<dim3(8, 8, 16), 256, 0, stream>>>(qb, kb, vbT, btab, attb);
    attn_mfma<false><<<dim3(4, 8, 16), 256, 0, stream>>>(qb, kb, vbT, mtab, attb);
    gemm_bias<float><<<dim3(93, 4), 256, 0, stream>>>(attb, wT[3], bias[3], (float*)d_out, MROWS);
}

// Round 6
// 231.439 us; speedup vs baseline: 1.6463x; 1.6463x over previous
//
#include <hip/hip_runtime.h>
#include <hip/hip_bf16.h>

typedef unsigned short u16;
typedef unsigned int u32;
typedef __attribute__((ext_vector_type(8))) short short8;   // 8 bf16 (4 VGPRs)
typedef __attribute__((ext_vector_type(4))) float f32x4;

#define NTOK 740
#define NTMP 256
#define NTGT 484
#define DM   512
#define MH   8
#define MROWS 11840   // B*NTOK = 16*740
#define KPAD 768

__device__ __forceinline__ float b2f(u16 u) {
    union { unsigned int i; float f; } x; x.i = ((unsigned int)u) << 16; return x.f;
}
__device__ __forceinline__ u16 f2b(float f) {
    union { float f; unsigned int i; } x; x.f = f;
    unsigned int r = x.i + 0x7FFFu + ((x.i >> 16) & 1u);   // RNE
    return (u16)(r >> 16);
}
struct alignas(8) us4 { u16 x, y, z, w; };

__device__ __forceinline__ void gload16(const void* g, void* l) {
    __builtin_amdgcn_global_load_lds(
        (const __attribute__((address_space(1))) void*)g,
        (__attribute__((address_space(3))) void*)l, 16, 0, 0);
}

// -------- weight transpose + bf16 convert: WT[n][k] = W[k][n], 512x512 --------
__global__ __launch_bounds__(256) void transpose512(const float* __restrict__ W,
                                                    u16* __restrict__ WT) {
    __shared__ float t[32][33];
    int bx = blockIdx.x, by = blockIdx.y;
    int tx = threadIdx.x;
    for (int i = threadIdx.y; i < 32; i += 8)
        t[i][tx] = W[(size_t)(by * 32 + i) * 512 + bx * 32 + tx];
    __syncthreads();
    for (int i = threadIdx.y; i < 32; i += 8)
        WT[(size_t)(bx * 32 + i) * 512 + by * 32 + tx] = f2b(t[tx][i]);
}

// ---------------- fused depthwise 3x3 conv + BN for q,k,v ----------------
__device__ __forceinline__ void conv_one(const float2* xv, const bool* ok, int c,
                                         const float* cw, const float* g, const float* bb,
                                         const float* m, const float* v, u16* out, size_t o) {
    float a0 = 0.f, a1 = 0.f;
#pragma unroll
    for (int tap = 0; tap < 9; ++tap) {
        a0 = fmaf(cw[c * 9 + tap], xv[tap].x, a0);
        a1 = fmaf(cw[(c + 1) * 9 + tap], xv[tap].y, a1);
    }
    const float i0 = g[c] * rsqrtf(v[c] + 1e-5f);
    const float i1 = g[c + 1] * rsqrtf(v[c + 1] + 1e-5f);
    const u32 pk = (u32)f2b((a0 - m[c]) * i0 + bb[c]) |
                   ((u32)f2b((a1 - m[c + 1]) * i1 + bb[c + 1]) << 16);
    *(u32*)(out + o) = pk;
}

__global__ __launch_bounds__(256) void conv_bn3(
    const float* __restrict__ x,
    const float* __restrict__ cw0, const float* __restrict__ g0, const float* __restrict__ b0,
    const float* __restrict__ m0, const float* __restrict__ v0,
    const float* __restrict__ cw1, const float* __restrict__ g1, const float* __restrict__ b1,
    const float* __restrict__ m1, const float* __restrict__ v1,
    const float* __restrict__ cw2, const float* __restrict__ g2, const float* __restrict__ b2_,
    const float* __restrict__ m2, const float* __restrict__ v2,
    u16* __restrict__ o0, u16* __restrict__ o1, u16* __restrict__ o2) {
    const int bn = blockIdx.x;
    const int b = bn / NTOK, n = bn % NTOK;
    const bool tmp = n < NTMP;
    const int L = tmp ? 16 : 22, base = tmp ? 0 : NTMP, p = n - base;
    const int ph = p / L, pw = p % L;
    int nb[9]; bool ok[9];
#pragma unroll
    for (int tap = 0; tap < 9; ++tap) {
        int dh = tap / 3 - 1, dw = tap % 3 - 1;
        int h2 = ph + dh, w2 = pw + dw;
        ok[tap] = (h2 >= 0 && h2 < L && w2 >= 0 && w2 < L);
        nb[tap] = ok[tap] ? (b * NTOK + base + h2 * L + w2) : 0;
    }
    const int c = threadIdx.x * 2;
    float2 xv[9];
#pragma unroll
    for (int tap = 0; tap < 9; ++tap)
        xv[tap] = ok[tap] ? *(const float2*)(x + (size_t)nb[tap] * DM + c) : float2{0.f, 0.f};
    const size_t o = (size_t)bn * DM + c;
    conv_one(xv, ok, c, cw0, g0, b0, m0, v0, o0, o);
    conv_one(xv, ok, c, cw1, g1, b1, m1, v1, o1, o);
    conv_one(xv, ok, c, cw2, g2, b2_, m2, v2, o2, o);
}

// ---------------- MFMA GEMM, 64x128 tile, global_load_lds staging ----------------
// MODE 0: bf16 out C[M,512]; MODE 1: f32 out; MODE 2: bf16 into vbT[b][h][d][k]
template <int MODE>
__global__ __launch_bounds__(256) void gemm64(const u16* __restrict__ A,
                                              const u16* __restrict__ BT,
                                              const float* __restrict__ bias,
                                              void* __restrict__ Cout) {
    __shared__ u16 As[2][64 * 32];
    __shared__ u16 Bs[2][128 * 32];
    const int tid = threadIdx.x;
    const int gm0 = blockIdx.x * 64;      // 185 exact (185*64 = 11840)
    const int gn0 = blockIdx.y * 128;
    const int lane = tid & 63, w = tid >> 6;
    const int lr = lane & 15, lg = lane >> 4;
    const int wm = (w >> 1) * 32, wn = (w & 1) * 64;

    // staging: content chunk pre-swizzled so linear LDS dest lands swizzled
    const int srow4 = lane >> 2;                 // 0..15 row-within-1KB
    const int sc = (lane & 3) ^ (srow4 & 3);     // content chunk for this lane
    const u16* asrc  = A  + (size_t)(gm0 + w * 16 + srow4) * 512 + sc * 8;
    const u16* bsrc0 = BT + (size_t)(gn0 + w * 32 + srow4) * 512 + sc * 8;
    const u16* bsrc1 = BT + (size_t)(gn0 + w * 32 + 16 + srow4) * 512 + sc * 8;

#define STAGEG(bf, koff) do { \
    gload16(asrc + (koff),  &As[bf][w * 512]); \
    gload16(bsrc0 + (koff), &Bs[bf][w * 1024]); \
    gload16(bsrc1 + (koff), &Bs[bf][w * 1024 + 512]); \
} while (0)

    f32x4 acc[2][4] = {};
    STAGEG(0, 0);
    for (int kt = 0; kt < 16; ++kt) {
        const int cur = kt & 1;
        if (kt < 15) {
            STAGEG(cur ^ 1, (kt + 1) * 32);
            asm volatile("s_waitcnt vmcnt(3)" ::: "memory");
        } else {
            asm volatile("s_waitcnt vmcnt(0)" ::: "memory");
        }
        __syncthreads();
        short8 af[2], bfr[4];
#pragma unroll
        for (int i = 0; i < 2; ++i)
            af[i] = *(const short8*)&As[cur][(wm + i * 16 + lr) * 32 + (lg ^ (lr & 3)) * 8];
#pragma unroll
        for (int j = 0; j < 4; ++j)
            bfr[j] = *(const short8*)&Bs[cur][(wn + j * 16 + lr) * 32 + (lg ^ (lr & 3)) * 8];
#pragma unroll
        for (int i = 0; i < 2; ++i)
#pragma unroll
            for (int j = 0; j < 4; ++j)
                acc[i][j] = __builtin_amdgcn_mfma_f32_16x16x32_bf16(af[i], bfr[j], acc[i][j], 0, 0, 0);
        __syncthreads();
    }
#undef STAGEG

#pragma unroll
    for (int i = 0; i < 2; ++i)
#pragma unroll
        for (int j = 0; j < 4; ++j) {
            const int gc = gn0 + wn + j * 16 + lr;
            const float bv = bias[gc];
#pragma unroll
            for (int r = 0; r < 4; ++r) {
                const int gr = gm0 + wm + i * 16 + lg * 4 + r;
                const float val = acc[i][j][r] + bv;
                if constexpr (MODE == 0) {
                    ((u16*)Cout)[(size_t)gr * 512 + gc] = f2b(val);
                } else if constexpr (MODE == 1) {
                    ((float*)Cout)[(size_t)gr * 512 + gc] = val;
                } else {
                    const int b2 = gr / NTOK, k = gr - b2 * NTOK;
                    const int hh = gc >> 6, d = gc & 63;
                    ((u16*)Cout)[((size_t)(b2 * MH + hh) * 64 + d) * KPAD + k] = f2b(val);
                }
            }
        }
}

// -------- bias tables (batch-independent) --------
__global__ __launch_bounds__(256) void build_bias_t(const float* __restrict__ rpb_t,
                                                    const float* __restrict__ tt,
                                                    const float* __restrict__ tg,
                                                    u16* __restrict__ btab) {
    const int q = blockIdx.x, h = blockIdx.y;
    const int qh = q / 22, qw = q % 22;
    const float tgv = tg[h * NTGT + q];
    for (int k = threadIdx.x; k < KPAD; k += 256) {
        float val;
        if (k < NTMP) val = tt[h * NTMP + k] + tgv;
        else if (k < NTOK) {
            const int kj = k - NTMP, kh = kj / 22, kw = kj % 22;
            val = rpb_t[((qh - kh + 21) * 43 + (qw - kw + 21)) * MH + h];
        } else val = -1e30f;
        btab[((size_t)(h * NTGT + q)) * KPAD + k] = f2b(val);
    }
}
__global__ __launch_bounds__(256) void build_bias_m(const float* __restrict__ rpb_m,
                                                    u16* __restrict__ mtab) {
    const int q = blockIdx.x, k = threadIdx.x;
    const int qh = q >> 4, qw = q & 15, kh = k >> 4, kw = k & 15;
    mtab[q * 256 + k] = f2b(rpb_m[(qh - kh + 15) * 31 + (qw - kw + 15)]);
}

// ---------------- merged MFMA flash attention (O^T form, 32-key chunks) ----------------
// grid.x: 0..7 target q-tiles, 8..11 temp q-tiles. 4 waves x 16 q-rows.
__global__ __launch_bounds__(256) void attn_all(const u16* __restrict__ qb,
                                                const u16* __restrict__ kb,
                                                const u16* __restrict__ vbT,
                                                const u16* __restrict__ btab,
                                                const u16* __restrict__ mtab,
                                                u16* __restrict__ attb) {
    __shared__ u16 Ks[2][32][64];    // keys x d (swizzled 16B chunks)
    __shared__ u16 VTs[2][64][32];   // d x keys (swizzled)
    __shared__ u16 Pb[4][16][32];    // per-wave P^T round-trip (swizzled)

    const int bx = blockIdx.x, h = blockIdx.y, b = blockIdx.z;
    const bool tgt = bx < 8;
    const int q0 = (tgt ? bx : bx - 8) * 64;
    const int NKr = tgt ? NTOK : NTMP;
    const int NCH = tgt ? 24 : 8;
    const int QTOT = tgt ? NTGT : NTMP;
    const int QOFF = tgt ? NTMP : 0;
    const int tid = threadIdx.x;
    const int w = tid >> 6, lane = tid & 63;
    const int lq = lane & 15, lg = lane >> 4;
    const size_t brow = (size_t)b * NTOK;

    int qmine = q0 + w * 16 + lq;
    if (qmine > QTOT - 1) qmine = QTOT - 1;
    const u16* trow = tgt ? (btab + ((size_t)(h * NTGT + qmine)) * KPAD)
                          : (mtab + qmine * 256);

    short8 qf[2];
#pragma unroll
    for (int dc = 0; dc < 2; ++dc)
        qf[dc] = *(const short8*)(qb + (brow + QOFF + qmine) * DM + h * 64 + dc * 32 + lg * 8);

    const int krow = tid >> 3, ksc = tid & 7;
    const int vrow = tid >> 2, vsc = tid & 3;
    const u16* kptr = kb + brow * DM + h * 64 + ksc * 8;
    const u16* vptr = vbT + (size_t)(b * MH + h) * 64 * KPAD + (size_t)vrow * KPAD + vsc * 8;

    float mrun = -1e30f, lrun = 0.f;
    f32x4 oT[4] = {};

    {   // prologue: stage chunk 0
        int4 kv = (krow < NKr) ? *(const int4*)(kptr + (size_t)krow * DM) : int4{0, 0, 0, 0};
        *(int4*)&Ks[0][krow][(ksc ^ (krow & 7)) * 8] = kv;
        int4 vv = *(const int4*)(vptr);
        *(int4*)&VTs[0][vrow][(vsc ^ (vrow & 3)) * 8] = vv;
    }
    us4 bc0 = *(const us4*)(trow + lg * 4);
    us4 bc1 = *(const us4*)(trow + 16 + lg * 4);
    __syncthreads();

    for (int kc = 0; kc < NCH; ++kc) {
        const int cur = kc & 1, nxt = cur ^ 1;
        const bool more = (kc + 1 < NCH);
        int4 nk = {0, 0, 0, 0}, nv = {0, 0, 0, 0};
        us4 bn0 = {0, 0, 0, 0}, bn1 = {0, 0, 0, 0};
        if (more) {
            const int key = (kc + 1) * 32 + krow;
            if (key < NKr) nk = *(const int4*)(kptr + (size_t)key * DM);
            nv = *(const int4*)(vptr + (kc + 1) * 32);
            bn0 = *(const us4*)(trow + (kc + 1) * 32 + lg * 4);
            bn1 = *(const us4*)(trow + (kc + 1) * 32 + 16 + lg * 4);
        }

        // ---- S^T: D[key][q], col=q=lq, row=key=sub*16+lg*4+r ----
        f32x4 s0 = {}, s1 = {};
#pragma unroll
        for (int dc = 0; dc < 2; ++dc) {
            short8 a0 = *(const short8*)&Ks[cur][lq][((dc * 4 + lg) ^ (lq & 7)) * 8];
            short8 a1 = *(const short8*)&Ks[cur][16 + lq][((dc * 4 + lg) ^ (lq & 7)) * 8];
            s0 = __builtin_amdgcn_mfma_f32_16x16x32_bf16(a0, qf[dc], s0, 0, 0, 0);
            s1 = __builtin_amdgcn_mfma_f32_16x16x32_bf16(a1, qf[dc], s1, 0, 0, 0);
        }
        float sv[8];
        sv[0] = fmaf(s0[0], 0.125f, b2f(bc0.x)); sv[1] = fmaf(s0[1], 0.125f, b2f(bc0.y));
        sv[2] = fmaf(s0[2], 0.125f, b2f(bc0.z)); sv[3] = fmaf(s0[3], 0.125f, b2f(bc0.w));
        sv[4] = fmaf(s1[0], 0.125f, b2f(bc1.x)); sv[5] = fmaf(s1[1], 0.125f, b2f(bc1.y));
        sv[6] = fmaf(s1[2], 0.125f, b2f(bc1.z)); sv[7] = fmaf(s1[3], 0.125f, b2f(bc1.w));

        // ---- online softmax; stats per q (lane-local, replicated over lg) ----
        float cm = sv[0];
#pragma unroll
        for (int i = 1; i < 8; ++i) cm = fmaxf(cm, sv[i]);
        cm = fmaxf(cm, __shfl_xor(cm, 16));
        cm = fmaxf(cm, __shfl_xor(cm, 32));
        const float mnew = fmaxf(mrun, cm);
        const float alpha = __expf(mrun - mnew);
        float pv[8]; float psum = 0.f;
#pragma unroll
        for (int i = 0; i < 8; ++i) { pv[i] = __expf(sv[i] - mnew); psum += pv[i]; }
        psum += __shfl_xor(psum, 16);
        psum += __shfl_xor(psum, 32);
        lrun = lrun * alpha + psum;
        mrun = mnew;

        us4 pw0, pw1;
        pw0.x = f2b(pv[0]); pw0.y = f2b(pv[1]); pw0.z = f2b(pv[2]); pw0.w = f2b(pv[3]);
        pw1.x = f2b(pv[4]); pw1.y = f2b(pv[5]); pw1.z = f2b(pv[6]); pw1.w = f2b(pv[7]);
        *(us4*)&Pb[w][lq][(((lg >> 1)) ^ (lq & 3)) * 8 + (lg & 1) * 4] = pw0;
        *(us4*)&Pb[w][lq][((2 + (lg >> 1)) ^ (lq & 3)) * 8 + (lg & 1) * 4] = pw1;

        // rescale O^T (cols = q = lq -> alpha lane-local)
#pragma unroll
        for (int t = 0; t < 4; ++t)
#pragma unroll
            for (int r = 0; r < 4; ++r) oT[t][r] *= alpha;

        asm volatile("s_waitcnt lgkmcnt(0)" ::: "memory");

        // ---- PV: O^T[d][q] += V^T[d][32k] * P^T[32k][q] ----
        short8 pf = *(const short8*)&Pb[w][lq][(lg ^ (lq & 3)) * 8];
#pragma unroll
        for (int t = 0; t < 4; ++t) {
            short8 vf = *(const short8*)&VTs[cur][t * 16 + lq][(lg ^ (lq & 3)) * 8];
            oT[t] = __builtin_amdgcn_mfma_f32_16x16x32_bf16(vf, pf, oT[t], 0, 0, 0);
        }

        if (more) {
            *(int4*)&Ks[nxt][krow][(ksc ^ (krow & 7)) * 8] = nk;
            *(int4*)&VTs[nxt][vrow][(vsc ^ (vrow & 3)) * 8] = nv;
            bc0 = bn0; bc1 = bn1;
        }
        __syncthreads();
    }

    // epilogue: O[q][d] store, q=lq lane-local, d = t*16+lg*4+r
    const float linv = 1.f / lrun;
    const int qrow = q0 + w * 16 + lq;
    if (qrow < QTOT) {
        u16* op = attb + (brow + QOFF + qrow) * DM + h * 64;
#pragma unroll
        for (int t = 0; t < 4; ++t) {
            us4 o;
            o.x = f2b(oT[t][0] * linv); o.y = f2b(oT[t][1] * linv);
            o.z = f2b(oT[t][2] * linv); o.w = f2b(oT[t][3] * linv);
            *(us4*)(op + t * 16 + lg * 4) = o;
        }
    }
}

// ---------------- launch ----------------
extern "C" void kernel_launch(void* const* d_in, const int* in_sizes, int n_in,
                              void* d_out, int out_size, void* d_ws, size_t ws_size,
                              hipStream_t stream) {
    const float* x = (const float*)d_in[0];
    const float* convw[3] = {(const float*)d_in[1], (const float*)d_in[6], (const float*)d_in[11]};
    const float* bng[3]   = {(const float*)d_in[2], (const float*)d_in[7], (const float*)d_in[12]};
    const float* bnb[3]   = {(const float*)d_in[3], (const float*)d_in[8], (const float*)d_in[13]};
    const float* bnm[3]   = {(const float*)d_in[4], (const float*)d_in[9], (const float*)d_in[14]};
    const float* bnv[3]   = {(const float*)d_in[5], (const float*)d_in[10], (const float*)d_in[15]};
    const float* w[4]     = {(const float*)d_in[16], (const float*)d_in[18], (const float*)d_in[20], (const float*)d_in[22]};
    const float* bias[4]  = {(const float*)d_in[17], (const float*)d_in[19], (const float*)d_in[21], (const float*)d_in[23]};
    const float* rpb_t = (const float*)d_in[24];
    const float* rpb_m = (const float*)d_in[25];
    const float* tt    = (const float*)d_in[26];
    const float* tg    = (const float*)d_in[27];

    char* ws = (char*)d_ws;
    u16* wT[4];
    for (int i = 0; i < 4; ++i) wT[i] = (u16*)(ws + (size_t)i * 524288);
    const size_t SEQ = (size_t)MROWS * DM * 2;   // 12,124,160 B
    u16* cbq  = (u16*)(ws + 2097152);
    u16* cbk  = (u16*)(ws + 2097152 + SEQ);
    u16* cbv  = (u16*)(ws + 2097152 + 2 * SEQ);
    u16* kbuf = (u16*)(ws + 2097152 + 3 * SEQ);
    u16* vbT  = (u16*)(ws + 2097152 + 4 * SEQ);                       // 12,582,912
    u16* btab = (u16*)(ws + 2097152 + 4 * SEQ + 12582912);            // 5,947,392
    u16* mtab = (u16*)(ws + 2097152 + 4 * SEQ + 12582912 + 5947392);  // 131,072
    u16* qbuf = cbv;   // cbv dead after V-GEMM
    u16* attb = cbq;   // cbq dead after Q-GEMM

    for (int i = 0; i < 4; ++i)
        transpose512<<<dim3(16, 16), dim3(32, 8), 0, stream>>>(w[i], wT[i]);
    build_bias_t<<<dim3(NTGT, MH), 256, 0, stream>>>(rpb_t, tt, tg, btab);
    build_bias_m<<<256, 256, 0, stream>>>(rpb_m, mtab);

    conv_bn3<<<MROWS, 256, 0, stream>>>(x,
        convw[0], bng[0], bnb[0], bnm[0], bnv[0],
        convw[1], bng[1], bnb[1], bnm[1], bnv[1],
        convw[2], bng[2], bnb[2], bnm[2], bnv[2],
        cbq, cbk, cbv);

    gemm64<2><<<dim3(185, 4), 256, 0, stream>>>(cbv, wT[2], bias[2], vbT);
    gemm64<0><<<dim3(185, 4), 256, 0, stream>>>(cbq, wT[0], bias[0], qbuf);
    gemm64<0><<<dim3(185, 4), 256, 0, stream>>>(cbk, wT[1], bias[1], kbuf);

    attn_all<<<dim3(12, 8, 16), 256, 0, stream>>>(qbuf, kbuf, vbT, btab, mtab, attb);

    gemm64<1><<<dim3(185, 4), 256, 0, stream>>>(attb, wT[3], bias[3], d_out);
}

// Round 7
// 199.484 us; speedup vs baseline: 1.9100x; 1.1602x over previous
//
#include <hip/hip_runtime.h>
#include <hip/hip_bf16.h>

typedef unsigned short u16;
typedef unsigned int u32;
typedef __attribute__((ext_vector_type(8))) short short8;   // 8 bf16 (4 VGPRs)
typedef __attribute__((ext_vector_type(4))) float f32x4;

#define NTOK 740
#define NTMP 256
#define NTGT 484
#define DM   512
#define MH   8
#define MROWS 11840   // B*NTOK = 16*740
#define KPAD 768

__device__ __forceinline__ float b2f(u16 u) {
    union { unsigned int i; float f; } x; x.i = ((unsigned int)u) << 16; return x.f;
}
__device__ __forceinline__ u16 f2b(float f) {
    union { float f; unsigned int i; } x; x.f = f;
    unsigned int r = x.i + 0x7FFFu + ((x.i >> 16) & 1u);   // RNE
    return (u16)(r >> 16);
}
struct alignas(8) us4 { u16 x, y, z, w; };

__device__ __forceinline__ void gload16(const void* g, void* l) {
    __builtin_amdgcn_global_load_lds(
        (const __attribute__((address_space(1))) void*)g,
        (__attribute__((address_space(3))) void*)l, 16, 0, 0);
}

// -------- weight transpose + bf16 convert: WT[n][k] = W[k][n], 512x512 --------
__global__ __launch_bounds__(256) void transpose512(const float* __restrict__ W,
                                                    u16* __restrict__ WT) {
    __shared__ float t[32][33];
    int bx = blockIdx.x, by = blockIdx.y;
    int tx = threadIdx.x;
    for (int i = threadIdx.y; i < 32; i += 8)
        t[i][tx] = W[(size_t)(by * 32 + i) * 512 + bx * 32 + tx];
    __syncthreads();
    for (int i = threadIdx.y; i < 32; i += 8)
        WT[(size_t)(bx * 32 + i) * 512 + by * 32 + tx] = f2b(t[tx][i]);
}

// -------- conv weight prep: cwf[tap][c] = cw[c][tap]*inv[c]; shift = beta - mu*inv --------
__global__ __launch_bounds__(512) void prep_conv(const float* __restrict__ cw,
                                                 const float* __restrict__ g,
                                                 const float* __restrict__ bb,
                                                 const float* __restrict__ m,
                                                 const float* __restrict__ v,
                                                 float* __restrict__ cwf,
                                                 float* __restrict__ shift) {
    const int tap = blockIdx.x, c = threadIdx.x;
    const float inv = g[c] * rsqrtf(v[c] + 1e-5f);
    cwf[tap * DM + c] = cw[c * 9 + tap] * inv;
    if (tap == 0) shift[c] = bb[c] - m[c] * inv;
}

// ---------------- fused depthwise 3x3 conv (+folded BN) for q,k,v ----------------
// 2 tokens/block, 128 threads x 4 channels each. Coalesced weight loads.
__global__ __launch_bounds__(256) void conv_bn3(
    const float* __restrict__ x,
    const float* __restrict__ cwf0, const float* __restrict__ sh0,
    const float* __restrict__ cwf1, const float* __restrict__ sh1,
    const float* __restrict__ cwf2, const float* __restrict__ sh2,
    u16* __restrict__ o0, u16* __restrict__ o1, u16* __restrict__ o2) {
    const int bn = blockIdx.x * 2 + (threadIdx.x >> 7);
    const int c = (threadIdx.x & 127) * 4;
    const int b = bn / NTOK, n = bn % NTOK;
    const bool tmp = n < NTMP;
    const int L = tmp ? 16 : 22, base = tmp ? 0 : NTMP, p = n - base;
    const int ph = p / L, pw = p % L;
    float4 xv[9];
#pragma unroll
    for (int tap = 0; tap < 9; ++tap) {
        const int dh = tap / 3 - 1, dw = tap % 3 - 1;
        const int h2 = ph + dh, w2 = pw + dw;
        const bool ok = (h2 >= 0 && h2 < L && w2 >= 0 && w2 < L);
        xv[tap] = ok ? *(const float4*)(x + (size_t)(b * NTOK + base + h2 * L + w2) * DM + c)
                     : float4{0.f, 0.f, 0.f, 0.f};
    }
    const size_t o = (size_t)bn * DM + c;
    const float* cwf[3] = {cwf0, cwf1, cwf2};
    const float* sh[3]  = {sh0, sh1, sh2};
    u16* out[3] = {o0, o1, o2};
#pragma unroll
    for (int br = 0; br < 3; ++br) {
        float4 acc = *(const float4*)(sh[br] + c);
#pragma unroll
        for (int tap = 0; tap < 9; ++tap) {
            const float4 wv = *(const float4*)(cwf[br] + tap * DM + c);
            acc.x = fmaf(wv.x, xv[tap].x, acc.x);
            acc.y = fmaf(wv.y, xv[tap].y, acc.y);
            acc.z = fmaf(wv.z, xv[tap].z, acc.z);
            acc.w = fmaf(wv.w, xv[tap].w, acc.w);
        }
        us4 r;
        r.x = f2b(acc.x); r.y = f2b(acc.y); r.z = f2b(acc.z); r.w = f2b(acc.w);
        *(us4*)(out[br] + o) = r;
    }
}

// ---------------- MFMA GEMM, 64x128 tile, global_load_lds staging ----------------
// MODE 0: bf16 out C[M,512]; MODE 1: f32 out; MODE 2: bf16 into vbT[b][h][d][k]
template <int MODE>
__global__ __launch_bounds__(256) void gemm64(const u16* __restrict__ A,
                                              const u16* __restrict__ BT,
                                              const float* __restrict__ bias,
                                              void* __restrict__ Cout) {
    __shared__ u16 As[2][64 * 32];
    __shared__ u16 Bs[2][128 * 32];
    const int tid = threadIdx.x;
    const int gm0 = blockIdx.x * 64;      // 185 exact (185*64 = 11840)
    const int gn0 = blockIdx.y * 128;
    const int lane = tid & 63, w = tid >> 6;
    const int lr = lane & 15, lg = lane >> 4;
    const int wm = (w >> 1) * 32, wn = (w & 1) * 64;

    // staging: content chunk pre-swizzled so linear LDS dest lands swizzled
    const int srow4 = lane >> 2;                 // 0..15 row-within-1KB
    const int sc = (lane & 3) ^ (srow4 & 3);     // content chunk for this lane
    const u16* asrc  = A  + (size_t)(gm0 + w * 16 + srow4) * 512 + sc * 8;
    const u16* bsrc0 = BT + (size_t)(gn0 + w * 32 + srow4) * 512 + sc * 8;
    const u16* bsrc1 = BT + (size_t)(gn0 + w * 32 + 16 + srow4) * 512 + sc * 8;

#define STAGEG(bf, koff) do { \
    gload16(asrc + (koff),  &As[bf][w * 512]); \
    gload16(bsrc0 + (koff), &Bs[bf][w * 1024]); \
    gload16(bsrc1 + (koff), &Bs[bf][w * 1024 + 512]); \
} while (0)

    f32x4 acc[2][4] = {};
    STAGEG(0, 0);
    for (int kt = 0; kt < 16; ++kt) {
        const int cur = kt & 1;
        if (kt < 15) {
            STAGEG(cur ^ 1, (kt + 1) * 32);
            asm volatile("s_waitcnt vmcnt(3)" ::: "memory");
        } else {
            asm volatile("s_waitcnt vmcnt(0)" ::: "memory");
        }
        __syncthreads();
        short8 af[2], bfr[4];
#pragma unroll
        for (int i = 0; i < 2; ++i)
            af[i] = *(const short8*)&As[cur][(wm + i * 16 + lr) * 32 + (lg ^ (lr & 3)) * 8];
#pragma unroll
        for (int j = 0; j < 4; ++j)
            bfr[j] = *(const short8*)&Bs[cur][(wn + j * 16 + lr) * 32 + (lg ^ (lr & 3)) * 8];
#pragma unroll
        for (int i = 0; i < 2; ++i)
#pragma unroll
            for (int j = 0; j < 4; ++j)
                acc[i][j] = __builtin_amdgcn_mfma_f32_16x16x32_bf16(af[i], bfr[j], acc[i][j], 0, 0, 0);
        __syncthreads();
    }
#undef STAGEG

#pragma unroll
    for (int i = 0; i < 2; ++i)
#pragma unroll
        for (int j = 0; j < 4; ++j) {
            const int gc = gn0 + wn + j * 16 + lr;
            const float bv = bias[gc];
#pragma unroll
            for (int r = 0; r < 4; ++r) {
                const int gr = gm0 + wm + i * 16 + lg * 4 + r;
                const float val = acc[i][j][r] + bv;
                if constexpr (MODE == 0) {
                    ((u16*)Cout)[(size_t)gr * 512 + gc] = f2b(val);
                } else if constexpr (MODE == 1) {
                    ((float*)Cout)[(size_t)gr * 512 + gc] = val;
                } else {
                    const int b2 = gr / NTOK, k = gr - b2 * NTOK;
                    const int hh = gc >> 6, d = gc & 63;
                    ((u16*)Cout)[((size_t)(b2 * MH + hh) * 64 + d) * KPAD + k] = f2b(val);
                }
            }
        }
}

// -------- bias tables (batch-independent) --------
__global__ __launch_bounds__(256) void build_bias_t(const float* __restrict__ rpb_t,
                                                    const float* __restrict__ tt,
                                                    const float* __restrict__ tg,
                                                    u16* __restrict__ btab) {
    const int q = blockIdx.x, h = blockIdx.y;
    const int qh = q / 22, qw = q % 22;
    const float tgv = tg[h * NTGT + q];
    for (int k = threadIdx.x; k < KPAD; k += 256) {
        float val;
        if (k < NTMP) val = tt[h * NTMP + k] + tgv;
        else if (k < NTOK) {
            const int kj = k - NTMP, kh = kj / 22, kw = kj % 22;
            val = rpb_t[((qh - kh + 21) * 43 + (qw - kw + 21)) * MH + h];
        } else val = -1e30f;
        btab[((size_t)(h * NTGT + q)) * KPAD + k] = f2b(val);
    }
}
__global__ __launch_bounds__(256) void build_bias_m(const float* __restrict__ rpb_m,
                                                    u16* __restrict__ mtab) {
    const int q = blockIdx.x, k = threadIdx.x;
    const int qh = q >> 4, qw = q & 15, kh = k >> 4, kw = k & 15;
    mtab[q * 256 + k] = f2b(rpb_m[(qh - kh + 15) * 31 + (qw - kw + 15)]);
}

// ---------------- merged MFMA flash attention (O^T form, 32-key chunks) ----------------
// grid.x: 0..7 target q-tiles, 8..11 temp q-tiles. 4 waves x 16 q-rows.
__global__ __launch_bounds__(256) void attn_all(const u16* __restrict__ qb,
                                                const u16* __restrict__ kb,
                                                const u16* __restrict__ vbT,
                                                const u16* __restrict__ btab,
                                                const u16* __restrict__ mtab,
                                                u16* __restrict__ attb) {
    __shared__ u16 Ks[2][32][64];    // keys x d (swizzled 16B chunks)
    __shared__ u16 VTs[2][64][32];   // d x keys (swizzled)
    __shared__ u16 Pb[4][16][32];    // per-wave P^T round-trip (swizzled)

    const int bx = blockIdx.x, h = blockIdx.y, b = blockIdx.z;
    const bool tgt = bx < 8;
    const int q0 = (tgt ? bx : bx - 8) * 64;
    const int NKr = tgt ? NTOK : NTMP;
    const int NCH = tgt ? 24 : 8;
    const int QTOT = tgt ? NTGT : NTMP;
    const int QOFF = tgt ? NTMP : 0;
    const int tid = threadIdx.x;
    const int w = tid >> 6, lane = tid & 63;
    const int lq = lane & 15, lg = lane >> 4;
    const size_t brow = (size_t)b * NTOK;

    int qmine = q0 + w * 16 + lq;
    if (qmine > QTOT - 1) qmine = QTOT - 1;
    const u16* trow = tgt ? (btab + ((size_t)(h * NTGT + qmine)) * KPAD)
                          : (mtab + qmine * 256);

    short8 qf[2];
#pragma unroll
    for (int dc = 0; dc < 2; ++dc)
        qf[dc] = *(const short8*)(qb + (brow + QOFF + qmine) * DM + h * 64 + dc * 32 + lg * 8);

    const int krow = tid >> 3, ksc = tid & 7;
    const int vrow = tid >> 2, vsc = tid & 3;
    const u16* kptr = kb + brow * DM + h * 64 + ksc * 8;
    const u16* vptr = vbT + (size_t)(b * MH + h) * 64 * KPAD + (size_t)vrow * KPAD + vsc * 8;

    float mrun = -1e30f, lrun = 0.f;
    f32x4 oT[4] = {};

    {   // prologue: stage chunk 0
        int4 kv = (krow < NKr) ? *(const int4*)(kptr + (size_t)krow * DM) : int4{0, 0, 0, 0};
        *(int4*)&Ks[0][krow][(ksc ^ (krow & 7)) * 8] = kv;
        int4 vv = *(const int4*)(vptr);
        *(int4*)&VTs[0][vrow][(vsc ^ (vrow & 3)) * 8] = vv;
    }
    us4 bc0 = *(const us4*)(trow + lg * 4);
    us4 bc1 = *(const us4*)(trow + 16 + lg * 4);
    __syncthreads();

    for (int kc = 0; kc < NCH; ++kc) {
        const int cur = kc & 1, nxt = cur ^ 1;
        const bool more = (kc + 1 < NCH);
        int4 nk = {0, 0, 0, 0}, nv = {0, 0, 0, 0};
        us4 bn0 = {0, 0, 0, 0}, bn1 = {0, 0, 0, 0};
        if (more) {
            const int key = (kc + 1) * 32 + krow;
            if (key < NKr) nk = *(const int4*)(kptr + (size_t)key * DM);
            nv = *(const int4*)(vptr + (kc + 1) * 32);
            bn0 = *(const us4*)(trow + (kc + 1) * 32 + lg * 4);
            bn1 = *(const us4*)(trow + (kc + 1) * 32 + 16 + lg * 4);
        }

        // ---- S^T: D[key][q], col=q=lq, row=key=sub*16+lg*4+r ----
        f32x4 s0 = {}, s1 = {};
#pragma unroll
        for (int dc = 0; dc < 2; ++dc) {
            short8 a0 = *(const short8*)&Ks[cur][lq][((dc * 4 + lg) ^ (lq & 7)) * 8];
            short8 a1 = *(const short8*)&Ks[cur][16 + lq][((dc * 4 + lg) ^ (lq & 7)) * 8];
            s0 = __builtin_amdgcn_mfma_f32_16x16x32_bf16(a0, qf[dc], s0, 0, 0, 0);
            s1 = __builtin_amdgcn_mfma_f32_16x16x32_bf16(a1, qf[dc], s1, 0, 0, 0);
        }
        float sv[8];
        sv[0] = fmaf(s0[0], 0.125f, b2f(bc0.x)); sv[1] = fmaf(s0[1], 0.125f, b2f(bc0.y));
        sv[2] = fmaf(s0[2], 0.125f, b2f(bc0.z)); sv[3] = fmaf(s0[3], 0.125f, b2f(bc0.w));
        sv[4] = fmaf(s1[0], 0.125f, b2f(bc1.x)); sv[5] = fmaf(s1[1], 0.125f, b2f(bc1.y));
        sv[6] = fmaf(s1[2], 0.125f, b2f(bc1.z)); sv[7] = fmaf(s1[3], 0.125f, b2f(bc1.w));

        // ---- online softmax; stats per q (lane-local, replicated over lg) ----
        float cm = sv[0];
#pragma unroll
        for (int i = 1; i < 8; ++i) cm = fmaxf(cm, sv[i]);
        cm = fmaxf(cm, __shfl_xor(cm, 16));
        cm = fmaxf(cm, __shfl_xor(cm, 32));
        const float mnew = fmaxf(mrun, cm);
        const float alpha = __expf(mrun - mnew);
        float pv[8]; float psum = 0.f;
#pragma unroll
        for (int i = 0; i < 8; ++i) { pv[i] = __expf(sv[i] - mnew); psum += pv[i]; }
        psum += __shfl_xor(psum, 16);
        psum += __shfl_xor(psum, 32);
        lrun = lrun * alpha + psum;
        mrun = mnew;

        us4 pw0, pw1;
        pw0.x = f2b(pv[0]); pw0.y = f2b(pv[1]); pw0.z = f2b(pv[2]); pw0.w = f2b(pv[3]);
        pw1.x = f2b(pv[4]); pw1.y = f2b(pv[5]); pw1.z = f2b(pv[6]); pw1.w = f2b(pv[7]);
        *(us4*)&Pb[w][lq][(((lg >> 1)) ^ (lq & 3)) * 8 + (lg & 1) * 4] = pw0;
        *(us4*)&Pb[w][lq][((2 + (lg >> 1)) ^ (lq & 3)) * 8 + (lg & 1) * 4] = pw1;

        // rescale O^T (cols = q = lq -> alpha lane-local)
#pragma unroll
        for (int t = 0; t < 4; ++t)
#pragma unroll
            for (int r = 0; r < 4; ++r) oT[t][r] *= alpha;

        asm volatile("s_waitcnt lgkmcnt(0)" ::: "memory");

        // ---- PV: O^T[d][q] += V^T[d][32k] * P^T[32k][q] ----
        short8 pf = *(const short8*)&Pb[w][lq][(lg ^ (lq & 3)) * 8];
#pragma unroll
        for (int t = 0; t < 4; ++t) {
            short8 vf = *(const short8*)&VTs[cur][t * 16 + lq][(lg ^ (lq & 3)) * 8];
            oT[t] = __builtin_amdgcn_mfma_f32_16x16x32_bf16(vf, pf, oT[t], 0, 0, 0);
        }

        if (more) {
            *(int4*)&Ks[nxt][krow][(ksc ^ (krow & 7)) * 8] = nk;
            *(int4*)&VTs[nxt][vrow][(vsc ^ (vrow & 3)) * 8] = nv;
            bc0 = bn0; bc1 = bn1;
        }
        __syncthreads();
    }

    // epilogue: O[q][d] store, q=lq lane-local, d = t*16+lg*4+r
    const float linv = 1.f / lrun;
    const int qrow = q0 + w * 16 + lq;
    if (qrow < QTOT) {
        u16* op = attb + (brow + QOFF + qrow) * DM + h * 64;
#pragma unroll
        for (int t = 0; t < 4; ++t) {
            us4 o;
            o.x = f2b(oT[t][0] * linv); o.y = f2b(oT[t][1] * linv);
            o.z = f2b(oT[t][2] * linv); o.w = f2b(oT[t][3] * linv);
            *(us4*)(op + t * 16 + lg * 4) = o;
        }
    }
}

// ---------------- launch ----------------
extern "C" void kernel_launch(void* const* d_in, const int* in_sizes, int n_in,
                              void* d_out, int out_size, void* d_ws, size_t ws_size,
                              hipStream_t stream) {
    const float* x = (const float*)d_in[0];
    const float* convw[3] = {(const float*)d_in[1], (const float*)d_in[6], (const float*)d_in[11]};
    const float* bng[3]   = {(const float*)d_in[2], (const float*)d_in[7], (const float*)d_in[12]};
    const float* bnb[3]   = {(const float*)d_in[3], (const float*)d_in[8], (const float*)d_in[13]};
    const float* bnm[3]   = {(const float*)d_in[4], (const float*)d_in[9], (const float*)d_in[14]};
    const float* bnv[3]   = {(const float*)d_in[5], (const float*)d_in[10], (const float*)d_in[15]};
    const float* w[4]     = {(const float*)d_in[16], (const float*)d_in[18], (const float*)d_in[20], (const float*)d_in[22]};
    const float* bias[4]  = {(const float*)d_in[17], (const float*)d_in[19], (const float*)d_in[21], (const float*)d_in[23]};
    const float* rpb_t = (const float*)d_in[24];
    const float* rpb_m = (const float*)d_in[25];
    const float* tt    = (const float*)d_in[26];
    const float* tg    = (const float*)d_in[27];

    char* ws = (char*)d_ws;
    u16* wT[4];
    for (int i = 0; i < 4; ++i) wT[i] = (u16*)(ws + (size_t)i * 524288);
    const size_t SEQ = (size_t)MROWS * DM * 2;   // 12,124,160 B
    u16* cbq  = (u16*)(ws + 2097152);
    u16* cbk  = (u16*)(ws + 2097152 + SEQ);
    u16* cbv  = (u16*)(ws + 2097152 + 2 * SEQ);
    u16* kbuf = (u16*)(ws + 2097152 + 3 * SEQ);
    u16* vbT  = (u16*)(ws + 2097152 + 4 * SEQ);                       // 12,582,912
    u16* btab = (u16*)(ws + 2097152 + 4 * SEQ + 12582912);            // 5,947,392
    u16* mtab = (u16*)(ws + 2097152 + 4 * SEQ + 12582912 + 5947392);  // 131,072
    float* cwf = (float*)(ws + 2097152 + 4 * SEQ + 12582912 + 5947392 + 131072); // 3*9*512*4 = 55,296
    float* shf = cwf + 3 * 9 * DM;                                    // 3*512*4
    u16* qbuf = cbv;   // cbv dead after V-GEMM
    u16* attb = cbq;   // cbq dead after Q-GEMM

    for (int i = 0; i < 4; ++i)
        transpose512<<<dim3(16, 16), dim3(32, 8), 0, stream>>>(w[i], wT[i]);
    build_bias_t<<<dim3(NTGT, MH), 256, 0, stream>>>(rpb_t, tt, tg, btab);
    build_bias_m<<<256, 256, 0, stream>>>(rpb_m, mtab);
    for (int br = 0; br < 3; ++br)
        prep_conv<<<9, 512, 0, stream>>>(convw[br], bng[br], bnb[br], bnm[br], bnv[br],
                                         cwf + br * 9 * DM, shf + br * DM);

    conv_bn3<<<MROWS / 2, 256, 0, stream>>>(x,
        cwf, shf, cwf + 9 * DM, shf + DM, cwf + 18 * DM, shf + 2 * DM,
        cbq, cbk, cbv);

    gemm64<2><<<dim3(185, 4), 256, 0, stream>>>(cbv, wT[2], bias[2], vbT);
    gemm64<0><<<dim3(185, 4), 256, 0, stream>>>(cbq, wT[0], bias[0], qbuf);
    gemm64<0><<<dim3(185, 4), 256, 0, stream>>>(cbk, wT[1], bias[1], kbuf);

    attn_all<<<dim3(12, 8, 16), 256, 0, stream>>>(qbuf, kbuf, vbT, btab, mtab, attb);

    gemm64<1><<<dim3(185, 4), 256, 0, stream>>>(attb, wT[3], bias[3], d_out);
}

// Round 10
// 186.296 us; speedup vs baseline: 2.0452x; 1.0708x over previous
//
#include <hip/hip_runtime.h>
#include <hip/hip_bf16.h>

typedef unsigned short u16;
typedef unsigned int u32;
typedef __attribute__((ext_vector_type(8))) short short8;   // 8 bf16 (4 VGPRs)
typedef __attribute__((ext_vector_type(4))) float f32x4;

#define NTOK 740
#define NTMP 256
#define NTGT 484
#define DM   512
#define MH   8
#define MROWS 11840   // B*NTOK = 16*740
#define KPAD 768
#define LOG2E 1.4426950408889634f

__device__ __forceinline__ float b2f(u16 u) {
    union { unsigned int i; float f; } x; x.i = ((unsigned int)u) << 16; return x.f;
}
__device__ __forceinline__ u16 f2b(float f) {
    union { float f; unsigned int i; } x; x.f = f;
    unsigned int r = x.i + 0x7FFFu + ((x.i >> 16) & 1u);   // RNE
    return (u16)(r >> 16);
}
__device__ __forceinline__ u32 pk2(float a, float b) {
    union { __hip_bfloat162 h; u32 u; } p;
    p.h = __float22bfloat162_rn(float2{a, b});
    return p.u;
}
__device__ __forceinline__ float fexp2(float x) {   // raw v_exp_f32 (input in log2 domain)
    return __builtin_amdgcn_exp2f(x);
}
struct alignas(8) us4 { u16 x, y, z, w; };

__device__ __forceinline__ void gload16(const void* g, void* l) {
    __builtin_amdgcn_global_load_lds(
        (const __attribute__((address_space(1))) void*)g,
        (__attribute__((address_space(3))) void*)l, 16, 0, 0);
}

// -------- weight transpose + bf16 convert: WT[n][k] = W[k][n], all 4 weights --------
__global__ __launch_bounds__(256) void transpose4(const float* __restrict__ w0,
                                                  const float* __restrict__ w1,
                                                  const float* __restrict__ w2,
                                                  const float* __restrict__ w3,
                                                  u16* __restrict__ wTbase) {
    __shared__ float t[32][33];
    const int z = blockIdx.z;
    const float* W = z == 0 ? w0 : z == 1 ? w1 : z == 2 ? w2 : w3;
    u16* WT = wTbase + (size_t)z * 262144;
    int bx = blockIdx.x, by = blockIdx.y;
    int tx = threadIdx.x;
    for (int i = threadIdx.y; i < 32; i += 8)
        t[i][tx] = W[(size_t)(by * 32 + i) * 512 + bx * 32 + tx];
    __syncthreads();
    for (int i = threadIdx.y; i < 32; i += 8)
        WT[(size_t)(bx * 32 + i) * 512 + by * 32 + tx] = f2b(t[tx][i]);
}

// -------- conv weight prep (3 branches): cwf[tap][c] = cw[c][tap]*inv; shift --------
__global__ __launch_bounds__(512) void prep_conv3(
    const float* __restrict__ cw0, const float* __restrict__ g0, const float* __restrict__ bb0,
    const float* __restrict__ m0, const float* __restrict__ v0,
    const float* __restrict__ cw1, const float* __restrict__ g1, const float* __restrict__ bb1,
    const float* __restrict__ m1, const float* __restrict__ v1,
    const float* __restrict__ cw2, const float* __restrict__ g2, const float* __restrict__ bb2,
    const float* __restrict__ m2, const float* __restrict__ v2,
    float* __restrict__ cwfb, float* __restrict__ shb) {
    const int tap = blockIdx.x, br = blockIdx.y, c = threadIdx.x;
    const float* cw = br == 0 ? cw0 : br == 1 ? cw1 : cw2;
    const float* g  = br == 0 ? g0  : br == 1 ? g1  : g2;
    const float* bb = br == 0 ? bb0 : br == 1 ? bb1 : bb2;
    const float* m  = br == 0 ? m0  : br == 1 ? m1  : m2;
    const float* v  = br == 0 ? v0  : br == 1 ? v1  : v2;
    const float inv = g[c] * rsqrtf(v[c] + 1e-5f);
    cwfb[(br * 9 + tap) * DM + c] = cw[c * 9 + tap] * inv;
    if (tap == 0) shb[br * DM + c] = bb[c] - m[c] * inv;
}

// ---------------- fused depthwise 3x3 conv (+folded BN) for q,k,v ----------------
__global__ __launch_bounds__(256) void conv_bn3(
    const float* __restrict__ x,
    const float* __restrict__ cwfb, const float* __restrict__ shb,
    u16* __restrict__ o0, u16* __restrict__ o1, u16* __restrict__ o2) {
    const int bn = blockIdx.x * 2 + (threadIdx.x >> 7);
    const int c = (threadIdx.x & 127) * 4;
    const int b = bn / NTOK, n = bn % NTOK;
    const bool tmp = n < NTMP;
    const int L = tmp ? 16 : 22, base = tmp ? 0 : NTMP, p = n - base;
    const int ph = p / L, pw = p % L;
    float4 xv[9];
#pragma unroll
    for (int tap = 0; tap < 9; ++tap) {
        const int dh = tap / 3 - 1, dw = tap % 3 - 1;
        const int h2 = ph + dh, w2 = pw + dw;
        const bool ok = (h2 >= 0 && h2 < L && w2 >= 0 && w2 < L);
        xv[tap] = ok ? *(const float4*)(x + (size_t)(b * NTOK + base + h2 * L + w2) * DM + c)
                     : float4{0.f, 0.f, 0.f, 0.f};
    }
    const size_t o = (size_t)bn * DM + c;
    u16* out[3] = {o0, o1, o2};
#pragma unroll
    for (int br = 0; br < 3; ++br) {
        float4 acc = *(const float4*)(shb + br * DM + c);
#pragma unroll
        for (int tap = 0; tap < 9; ++tap) {
            const float4 wv = *(const float4*)(cwfb + (br * 9 + tap) * DM + c);
            acc.x = fmaf(wv.x, xv[tap].x, acc.x);
            acc.y = fmaf(wv.y, xv[tap].y, acc.y);
            acc.z = fmaf(wv.z, xv[tap].z, acc.z);
            acc.w = fmaf(wv.w, xv[tap].w, acc.w);
        }
        us4 r;
        r.x = f2b(acc.x); r.y = f2b(acc.y); r.z = f2b(acc.z); r.w = f2b(acc.w);
        *(us4*)(out[br] + o) = r;
    }
}

// ---------------- shared GEMM body macro (64x128 tile, global_load_lds) ----------------
#define GEMM_BODY(A, BT)                                                             \
    const int tid = threadIdx.x;                                                     \
    const int gm0 = blockIdx.x * 64;                                                 \
    const int gn0 = blockIdx.y * 128;                                                \
    const int lane = tid & 63, w = tid >> 6;                                         \
    const int lr = lane & 15, lg = lane >> 4;                                        \
    const int wm = (w >> 1) * 32, wn = (w & 1) * 64;                                 \
    const int srow4 = lane >> 2;                                                     \
    const int sc = (lane & 3) ^ (srow4 & 3);                                         \
    const u16* asrc  = A  + (size_t)(gm0 + w * 16 + srow4) * 512 + sc * 8;           \
    const u16* bsrc0 = BT + (size_t)(gn0 + w * 32 + srow4) * 512 + sc * 8;           \
    const u16* bsrc1 = BT + (size_t)(gn0 + w * 32 + 16 + srow4) * 512 + sc * 8;      \
    f32x4 acc[2][4] = {};                                                            \
    gload16(asrc, &As[0][w * 512]);                                                  \
    gload16(bsrc0, &Bs[0][w * 1024]);                                                \
    gload16(bsrc1, &Bs[0][w * 1024 + 512]);                                          \
    for (int kt = 0; kt < 16; ++kt) {                                                \
        const int cur = kt & 1;                                                      \
        if (kt < 15) {                                                               \
            gload16(asrc + (kt + 1) * 32, &As[cur ^ 1][w * 512]);                    \
            gload16(bsrc0 + (kt + 1) * 32, &Bs[cur ^ 1][w * 1024]);                  \
            gload16(bsrc1 + (kt + 1) * 32, &Bs[cur ^ 1][w * 1024 + 512]);            \
            asm volatile("s_waitcnt vmcnt(3)" ::: "memory");                         \
        } else {                                                                     \
            asm volatile("s_waitcnt vmcnt(0)" ::: "memory");                         \
        }                                                                            \
        __syncthreads();                                                             \
        short8 af[2], bfr[4];                                                        \
        _Pragma("unroll")                                                            \
        for (int i = 0; i < 2; ++i)                                                  \
            af[i] = *(const short8*)&As[cur][(wm + i * 16 + lr) * 32 + (lg ^ (lr & 3)) * 8]; \
        _Pragma("unroll")                                                            \
        for (int j = 0; j < 4; ++j)                                                  \
            bfr[j] = *(const short8*)&Bs[cur][(wn + j * 16 + lr) * 32 + (lg ^ (lr & 3)) * 8]; \
        _Pragma("unroll")                                                            \
        for (int i = 0; i < 2; ++i)                                                  \
            _Pragma("unroll")                                                        \
            for (int j = 0; j < 4; ++j)                                              \
                acc[i][j] = __builtin_amdgcn_mfma_f32_16x16x32_bf16(af[i], bfr[j], acc[i][j], 0, 0, 0); \
        __syncthreads();                                                             \
    }

// Q/K/V GEMMs: z = blockIdx.z + zbase selects branch. z==2 writes vbT layout.
// zbase split keeps the cbv->qbuf aliasing safe (V launch completes first).
__global__ __launch_bounds__(256) void gemm_qkv(
    const u16* __restrict__ Aq, const u16* __restrict__ Ak, const u16* __restrict__ Av,
    const u16* __restrict__ wTb, const float* __restrict__ bq,
    const float* __restrict__ bk, const float* __restrict__ bv,
    u16* __restrict__ qout, u16* __restrict__ kout, u16* __restrict__ vbT, int zbase) {
    __shared__ u16 As[2][64 * 32];
    __shared__ u16 Bs[2][128 * 32];
    const int z = blockIdx.z + zbase;
    const u16* A = z == 0 ? Aq : z == 1 ? Ak : Av;
    const u16* BT = wTb + (size_t)z * 262144;
    const float* bias = z == 0 ? bq : z == 1 ? bk : bv;
    GEMM_BODY(A, BT)
    u16* lin = z == 0 ? qout : kout;
#pragma unroll
    for (int i = 0; i < 2; ++i)
#pragma unroll
        for (int j = 0; j < 4; ++j) {
            const int gc = gn0 + wn + j * 16 + lr;
            const float bvl = bias[gc];
#pragma unroll
            for (int r = 0; r < 4; ++r) {
                const int gr = gm0 + wm + i * 16 + lg * 4 + r;
                const float val = acc[i][j][r] + bvl;
                if (z == 2) {
                    const int b2 = gr / NTOK, k = gr - b2 * NTOK;
                    const int hh = gc >> 6, d = gc & 63;
                    vbT[((size_t)(b2 * MH + hh) * 64 + d) * KPAD + k] = f2b(val);
                } else {
                    lin[(size_t)gr * 512 + gc] = f2b(val);
                }
            }
        }
}

// final projection GEMM: f32 out
__global__ __launch_bounds__(256) void gemm_out(const u16* __restrict__ Ain,
                                                const u16* __restrict__ BTin,
                                                const float* __restrict__ bias,
                                                float* __restrict__ C) {
    __shared__ u16 As[2][64 * 32];
    __shared__ u16 Bs[2][128 * 32];
    GEMM_BODY(Ain, BTin)
#pragma unroll
    for (int i = 0; i < 2; ++i)
#pragma unroll
        for (int j = 0; j < 4; ++j) {
            const int gc = gn0 + wn + j * 16 + lr;
            const float bvl = bias[gc];
#pragma unroll
            for (int r = 0; r < 4; ++r) {
                const int gr = gm0 + wm + i * 16 + lg * 4 + r;
                C[(size_t)gr * 512 + gc] = acc[i][j][r] + bvl;
            }
        }
}

// -------- bias tables, pre-scaled by log2(e) (softmax runs in exp2 domain) --------
__global__ __launch_bounds__(256) void build_bias_t(const float* __restrict__ rpb_t,
                                                    const float* __restrict__ tt,
                                                    const float* __restrict__ tg,
                                                    u16* __restrict__ btab) {
    const int q = blockIdx.x, h = blockIdx.y;
    const int qh = q / 22, qw = q % 22;
    const float tgv = tg[h * NTGT + q];
    for (int k = threadIdx.x; k < KPAD; k += 256) {
        float val;
        if (k < NTMP) val = (tt[h * NTMP + k] + tgv) * LOG2E;
        else if (k < NTOK) {
            const int kj = k - NTMP, kh = kj / 22, kw = kj % 22;
            val = rpb_t[((qh - kh + 21) * 43 + (qw - kw + 21)) * MH + h] * LOG2E;
        } else val = -1e30f;
        btab[((size_t)(h * NTGT + q)) * KPAD + k] = f2b(val);
    }
}
__global__ __launch_bounds__(256) void build_bias_m(const float* __restrict__ rpb_m,
                                                    u16* __restrict__ mtab) {
    const int q = blockIdx.x, k = threadIdx.x;
    const int qh = q >> 4, qw = q & 15, kh = k >> 4, kw = k & 15;
    mtab[q * 256 + k] = f2b(rpb_m[(qh - kh + 15) * 31 + (qw - kw + 15)] * LOG2E);
}

// ---------------- merged MFMA flash attention (O^T form, 32-key chunks) ----------------
__global__ __launch_bounds__(256) void attn_all(const u16* __restrict__ qb,
                                                const u16* __restrict__ kb,
                                                const u16* __restrict__ vbT,
                                                const u16* __restrict__ btab,
                                                const u16* __restrict__ mtab,
                                                u16* __restrict__ attb) {
    __shared__ u16 Ks[2][32][64];    // keys x d  (8-chunk swizzle, 128B rows)
    __shared__ u16 VTs[2][64][32];   // d x keys  (4-chunk swizzle incl. >>2 term)
    __shared__ u16 Pb[4][16][32];    // per-wave P^T round-trip (4-chunk swizzle)

    const int bx = blockIdx.x, h = blockIdx.y, b = blockIdx.z;
    const bool tgt = bx < 8;
    const int q0 = (tgt ? bx : bx - 8) * 64;
    const int NKr = tgt ? NTOK : NTMP;
    const int NCH = tgt ? 24 : 8;
    const int QTOT = tgt ? NTGT : NTMP;
    const int QOFF = tgt ? NTMP : 0;
    const int tid = threadIdx.x;
    const int w = tid >> 6, lane = tid & 63;
    const int lq = lane & 15, lg = lane >> 4;
    const int fq = (lq & 3) ^ ((lq >> 2) & 3);      // phase-safe 4-chunk swizzle
    const size_t brow = (size_t)b * NTOK;
    const float SCL = 0.125f * LOG2E;

    int qmine = q0 + w * 16 + lq;
    if (qmine > QTOT - 1) qmine = QTOT - 1;
    const u16* trow = tgt ? (btab + ((size_t)(h * NTGT + qmine)) * KPAD)
                          : (mtab + qmine * 256);

    short8 qf[2];
#pragma unroll
    for (int dc = 0; dc < 2; ++dc)
        qf[dc] = *(const short8*)(qb + (brow + QOFF + qmine) * DM + h * 64 + dc * 32 + lg * 8);

    const int krow = tid >> 3, ksc = tid & 7;
    const int vrow = tid >> 2, vsc = tid & 3;
    const int fv = (vrow & 3) ^ ((vrow >> 2) & 3);
    const u16* kptr = kb + brow * DM + h * 64 + ksc * 8;
    const u16* vptr = vbT + (size_t)(b * MH + h) * 64 * KPAD + (size_t)vrow * KPAD + vsc * 8;

    float mrun = -1e30f, lrun = 0.f;
    f32x4 oT[4] = {};

    {   // prologue: stage chunk 0
        int4 kv = (krow < NKr) ? *(const int4*)(kptr + (size_t)krow * DM) : int4{0, 0, 0, 0};
        *(int4*)&Ks[0][krow][(ksc ^ (krow & 7)) * 8] = kv;
        int4 vv = *(const int4*)(vptr);
        *(int4*)&VTs[0][vrow][(vsc ^ fv) * 8] = vv;
    }
    us4 bc0 = *(const us4*)(trow + lg * 4);
    us4 bc1 = *(const us4*)(trow + 16 + lg * 4);
    __syncthreads();

    for (int kc = 0; kc < NCH; ++kc) {
        const int cur = kc & 1, nxt = cur ^ 1;
        const bool more = (kc + 1 < NCH);
        int4 nk = {0, 0, 0, 0}, nv = {0, 0, 0, 0};
        us4 bn0 = {0, 0, 0, 0}, bn1 = {0, 0, 0, 0};
        if (more) {
            const int key = (kc + 1) * 32 + krow;
            if (key < NKr) nk = *(const int4*)(kptr + (size_t)key * DM);
            nv = *(const int4*)(vptr + (kc + 1) * 32);
            bn0 = *(const us4*)(trow + (kc + 1) * 32 + lg * 4);
            bn1 = *(const us4*)(trow + (kc + 1) * 32 + 16 + lg * 4);
        }

        // ---- S^T: D[key][q] ----
        f32x4 s0 = {}, s1 = {};
        __builtin_amdgcn_s_setprio(1);
#pragma unroll
        for (int dc = 0; dc < 2; ++dc) {
            short8 a0 = *(const short8*)&Ks[cur][lq][((dc * 4 + lg) ^ (lq & 7)) * 8];
            short8 a1 = *(const short8*)&Ks[cur][16 + lq][((dc * 4 + lg) ^ (lq & 7)) * 8];
            s0 = __builtin_amdgcn_mfma_f32_16x16x32_bf16(a0, qf[dc], s0, 0, 0, 0);
            s1 = __builtin_amdgcn_mfma_f32_16x16x32_bf16(a1, qf[dc], s1, 0, 0, 0);
        }
        __builtin_amdgcn_s_setprio(0);
        float sv[8];
        sv[0] = fmaf(s0[0], SCL, b2f(bc0.x)); sv[1] = fmaf(s0[1], SCL, b2f(bc0.y));
        sv[2] = fmaf(s0[2], SCL, b2f(bc0.z)); sv[3] = fmaf(s0[3], SCL, b2f(bc0.w));
        sv[4] = fmaf(s1[0], SCL, b2f(bc1.x)); sv[5] = fmaf(s1[1], SCL, b2f(bc1.y));
        sv[6] = fmaf(s1[2], SCL, b2f(bc1.z)); sv[7] = fmaf(s1[3], SCL, b2f(bc1.w));

        // ---- online softmax in exp2 domain; stats lane-local per q ----
        float cm = sv[0];
#pragma unroll
        for (int i = 1; i < 8; ++i) cm = fmaxf(cm, sv[i]);
        cm = fmaxf(cm, __shfl_xor(cm, 16));
        cm = fmaxf(cm, __shfl_xor(cm, 32));
        if (!__all(cm <= mrun)) {                    // defer-max: exact skip
            const float mnew = fmaxf(mrun, cm);
            const float alpha = fexp2(mrun - mnew);
#pragma unroll
            for (int t = 0; t < 4; ++t)
#pragma unroll
                for (int r = 0; r < 4; ++r) oT[t][r] *= alpha;
            lrun *= alpha;
            mrun = mnew;
        }
        float pv[8]; float psum = 0.f;
#pragma unroll
        for (int i = 0; i < 8; ++i) { pv[i] = fexp2(sv[i] - mrun); psum += pv[i]; }

        const int c0 = (((lg >> 1) ^ fq) & 3) * 8 + (lg & 1) * 4;
        const int c1 = (((2 + (lg >> 1)) ^ fq) & 3) * 8 + (lg & 1) * 4;
        *(uint2*)&Pb[w][lq][c0] = uint2{pk2(pv[0], pv[1]), pk2(pv[2], pv[3])};
        *(uint2*)&Pb[w][lq][c1] = uint2{pk2(pv[4], pv[5]), pk2(pv[6], pv[7])};

        psum += __shfl_xor(psum, 16);
        psum += __shfl_xor(psum, 32);
        lrun += psum;

        asm volatile("s_waitcnt lgkmcnt(0)" ::: "memory");

        // ---- PV: O^T[d][q] += V^T[d][32k] * P^T[32k][q] ----
        short8 pf = *(const short8*)&Pb[w][lq][((lg ^ fq) & 3) * 8];
        __builtin_amdgcn_s_setprio(1);
#pragma unroll
        for (int t = 0; t < 4; ++t) {
            short8 vf = *(const short8*)&VTs[cur][t * 16 + lq][((lg ^ fq) & 3) * 8];
            oT[t] = __builtin_amdgcn_mfma_f32_16x16x32_bf16(vf, pf, oT[t], 0, 0, 0);
        }
        __builtin_amdgcn_s_setprio(0);

        if (more) {
            *(int4*)&Ks[nxt][krow][(ksc ^ (krow & 7)) * 8] = nk;
            *(int4*)&VTs[nxt][vrow][(vsc ^ fv) * 8] = nv;
            bc0 = bn0; bc1 = bn1;
        }
        __syncthreads();
    }

    // epilogue: O[q][d] store, q=lq lane-local, d = t*16+lg*4..+3
    const float linv = 1.f / lrun;
    const int qrow = q0 + w * 16 + lq;
    if (qrow < QTOT) {
        u16* op = attb + (brow + QOFF + qrow) * DM + h * 64;
#pragma unroll
        for (int t = 0; t < 4; ++t)
            *(uint2*)(op + t * 16 + lg * 4) =
                uint2{pk2(oT[t][0] * linv, oT[t][1] * linv),
                      pk2(oT[t][2] * linv, oT[t][3] * linv)};
    }
}

// ---------------- launch ----------------
extern "C" void kernel_launch(void* const* d_in, const int* in_sizes, int n_in,
                              void* d_out, int out_size, void* d_ws, size_t ws_size,
                              hipStream_t stream) {
    const float* x = (const float*)d_in[0];
    const float* convw[3] = {(const float*)d_in[1], (const float*)d_in[6], (const float*)d_in[11]};
    const float* bng[3]   = {(const float*)d_in[2], (const float*)d_in[7], (const float*)d_in[12]};
    const float* bnb[3]   = {(const float*)d_in[3], (const float*)d_in[8], (const float*)d_in[13]};
    const float* bnm[3]   = {(const float*)d_in[4], (const float*)d_in[9], (const float*)d_in[14]};
    const float* bnv[3]   = {(const float*)d_in[5], (const float*)d_in[10], (const float*)d_in[15]};
    const float* w[4]     = {(const float*)d_in[16], (const float*)d_in[18], (const float*)d_in[20], (const float*)d_in[22]};
    const float* bias[4]  = {(const float*)d_in[17], (const float*)d_in[19], (const float*)d_in[21], (const float*)d_in[23]};
    const float* rpb_t = (const float*)d_in[24];
    const float* rpb_m = (const float*)d_in[25];
    const float* tt    = (const float*)d_in[26];
    const float* tg    = (const float*)d_in[27];

    char* ws = (char*)d_ws;
    u16* wTb = (u16*)ws;                                               // 4 x 512KB
    const size_t SEQ = (size_t)MROWS * DM * 2;   // 12,124,160 B
    u16* cbq  = (u16*)(ws + 2097152);
    u16* cbk  = (u16*)(ws + 2097152 + SEQ);
    u16* cbv  = (u16*)(ws + 2097152 + 2 * SEQ);
    u16* kbuf = (u16*)(ws + 2097152 + 3 * SEQ);
    u16* vbT  = (u16*)(ws + 2097152 + 4 * SEQ);                       // 12,582,912
    u16* btab = (u16*)(ws + 2097152 + 4 * SEQ + 12582912);            // 5,947,392
    u16* mtab = (u16*)(ws + 2097152 + 4 * SEQ + 12582912 + 5947392);  // 131,072
    float* cwf = (float*)(ws + 2097152 + 4 * SEQ + 12582912 + 5947392 + 131072);
    float* shf = cwf + 3 * 9 * DM;
    u16* qbuf = cbv;   // cbv dead after V-GEMM launch (ordered before Q/K launch)
    u16* attb = cbq;   // cbq dead after Q-GEMM

    transpose4<<<dim3(16, 16, 4), dim3(32, 8), 0, stream>>>(w[0], w[1], w[2], w[3], wTb);
    prep_conv3<<<dim3(9, 3), 512, 0, stream>>>(
        convw[0], bng[0], bnb[0], bnm[0], bnv[0],
        convw[1], bng[1], bnb[1], bnm[1], bnv[1],
        convw[2], bng[2], bnb[2], bnm[2], bnv[2], cwf, shf);
    build_bias_t<<<dim3(NTGT, MH), 256, 0, stream>>>(rpb_t, tt, tg, btab);
    build_bias_m<<<256, 256, 0, stream>>>(rpb_m, mtab);

    conv_bn3<<<MROWS / 2, 256, 0, stream>>>(x, cwf, shf, cbq, cbk, cbv);

    // V first (reads cbv), then Q+K (Q writes qbuf==cbv) — stream order makes it safe
    gemm_qkv<<<dim3(185, 4, 1), 256, 0, stream>>>(cbq, cbk, cbv, wTb,
                                                  bias[0], bias[1], bias[2],
                                                  qbuf, kbuf, vbT, 2);
    gemm_qkv<<<dim3(185, 4, 2), 256, 0, stream>>>(cbq, cbk, cbv, wTb,
                                                  bias[0], bias[1], bias[2],
                                                  qbuf, kbuf, vbT, 0);

    attn_all<<<dim3(12, 8, 16), 256, 0, stream>>>(qbuf, kbuf, vbT, btab, mtab, attb);

    gemm_out<<<dim3(185, 4), 256, 0, stream>>>(attb, wTb + 3 * 262144, bias[3], (float*)d_out);
}

// Round 11
// 184.622 us; speedup vs baseline: 2.0637x; 1.0091x over previous
//
#include <hip/hip_runtime.h>
#include <hip/hip_bf16.h>

typedef unsigned short u16;
typedef unsigned int u32;
typedef __attribute__((ext_vector_type(8))) short short8;   // 8 bf16 (4 VGPRs)
typedef __attribute__((ext_vector_type(4))) float f32x4;

#define NTOK 740
#define NTMP 256
#define NTGT 484
#define DM   512
#define MH   8
#define MROWS 11840   // B*NTOK = 16*740
#define KPAD 768
#define LOG2E 1.4426950408889634f

__device__ __forceinline__ float b2f(u16 u) {
    union { unsigned int i; float f; } x; x.i = ((unsigned int)u) << 16; return x.f;
}
__device__ __forceinline__ u16 f2b(float f) {
    union { float f; unsigned int i; } x; x.f = f;
    unsigned int r = x.i + 0x7FFFu + ((x.i >> 16) & 1u);   // RNE
    return (u16)(r >> 16);
}
__device__ __forceinline__ u32 pk2(float a, float b) {
    union { __hip_bfloat162 h; u32 u; } p;
    p.h = __float22bfloat162_rn(float2{a, b});
    return p.u;
}
__device__ __forceinline__ float fexp2(float x) {   // raw v_exp_f32 (input in log2 domain)
    return __builtin_amdgcn_exp2f(x);
}
struct alignas(8) us4 { u16 x, y, z, w; };

__device__ __forceinline__ void gload16(const void* g, void* l) {
    __builtin_amdgcn_global_load_lds(
        (const __attribute__((address_space(1))) void*)g,
        (__attribute__((address_space(3))) void*)l, 16, 0, 0);
}

// -------- weight transpose + bf16 convert: WT[n][k] = W[k][n], all 4 weights --------
__global__ __launch_bounds__(256) void transpose4(const float* __restrict__ w0,
                                                  const float* __restrict__ w1,
                                                  const float* __restrict__ w2,
                                                  const float* __restrict__ w3,
                                                  u16* __restrict__ wTbase) {
    __shared__ float t[32][33];
    const int z = blockIdx.z;
    const float* W = z == 0 ? w0 : z == 1 ? w1 : z == 2 ? w2 : w3;
    u16* WT = wTbase + (size_t)z * 262144;
    int bx = blockIdx.x, by = blockIdx.y;
    int tx = threadIdx.x;
    for (int i = threadIdx.y; i < 32; i += 8)
        t[i][tx] = W[(size_t)(by * 32 + i) * 512 + bx * 32 + tx];
    __syncthreads();
    for (int i = threadIdx.y; i < 32; i += 8)
        WT[(size_t)(bx * 32 + i) * 512 + by * 32 + tx] = f2b(t[tx][i]);
}

// -------- conv weight prep (3 branches): cwf[tap][c] = cw[c][tap]*inv; shift --------
__global__ __launch_bounds__(512) void prep_conv3(
    const float* __restrict__ cw0, const float* __restrict__ g0, const float* __restrict__ bb0,
    const float* __restrict__ m0, const float* __restrict__ v0,
    const float* __restrict__ cw1, const float* __restrict__ g1, const float* __restrict__ bb1,
    const float* __restrict__ m1, const float* __restrict__ v1,
    const float* __restrict__ cw2, const float* __restrict__ g2, const float* __restrict__ bb2,
    const float* __restrict__ m2, const float* __restrict__ v2,
    float* __restrict__ cwfb, float* __restrict__ shb) {
    const int tap = blockIdx.x, br = blockIdx.y, c = threadIdx.x;
    const float* cw = br == 0 ? cw0 : br == 1 ? cw1 : cw2;
    const float* g  = br == 0 ? g0  : br == 1 ? g1  : g2;
    const float* bb = br == 0 ? bb0 : br == 1 ? bb1 : bb2;
    const float* m  = br == 0 ? m0  : br == 1 ? m1  : m2;
    const float* v  = br == 0 ? v0  : br == 1 ? v1  : v2;
    const float inv = g[c] * rsqrtf(v[c] + 1e-5f);
    cwfb[(br * 9 + tap) * DM + c] = cw[c * 9 + tap] * inv;
    if (tap == 0) shb[br * DM + c] = bb[c] - m[c] * inv;
}

// ---------------- fused depthwise 3x3 conv (+folded BN) for q,k,v ----------------
__global__ __launch_bounds__(256) void conv_bn3(
    const float* __restrict__ x,
    const float* __restrict__ cwfb, const float* __restrict__ shb,
    u16* __restrict__ o0, u16* __restrict__ o1, u16* __restrict__ o2) {
    const int bn = blockIdx.x * 2 + (threadIdx.x >> 7);
    const int c = (threadIdx.x & 127) * 4;
    const int b = bn / NTOK, n = bn % NTOK;
    const bool tmp = n < NTMP;
    const int L = tmp ? 16 : 22, base = tmp ? 0 : NTMP, p = n - base;
    const int ph = p / L, pw = p % L;
    float4 xv[9];
#pragma unroll
    for (int tap = 0; tap < 9; ++tap) {
        const int dh = tap / 3 - 1, dw = tap % 3 - 1;
        const int h2 = ph + dh, w2 = pw + dw;
        const bool ok = (h2 >= 0 && h2 < L && w2 >= 0 && w2 < L);
        xv[tap] = ok ? *(const float4*)(x + (size_t)(b * NTOK + base + h2 * L + w2) * DM + c)
                     : float4{0.f, 0.f, 0.f, 0.f};
    }
    const size_t o = (size_t)bn * DM + c;
    u16* out[3] = {o0, o1, o2};
#pragma unroll
    for (int br = 0; br < 3; ++br) {
        float4 acc = *(const float4*)(shb + br * DM + c);
#pragma unroll
        for (int tap = 0; tap < 9; ++tap) {
            const float4 wv = *(const float4*)(cwfb + (br * 9 + tap) * DM + c);
            acc.x = fmaf(wv.x, xv[tap].x, acc.x);
            acc.y = fmaf(wv.y, xv[tap].y, acc.y);
            acc.z = fmaf(wv.z, xv[tap].z, acc.z);
            acc.w = fmaf(wv.w, xv[tap].w, acc.w);
        }
        us4 r;
        r.x = f2b(acc.x); r.y = f2b(acc.y); r.z = f2b(acc.z); r.w = f2b(acc.w);
        *(us4*)(out[br] + o) = r;
    }
}

// ---------------- shared GEMM body macro (64x128 tile, global_load_lds) ----------------
#define GEMM_BODY(A, BT)                                                             \
    const int tid = threadIdx.x;                                                     \
    const int gm0 = blockIdx.x * 64;                                                 \
    const int gn0 = blockIdx.y * 128;                                                \
    const int lane = tid & 63, w = tid >> 6;                                         \
    const int lr = lane & 15, lg = lane >> 4;                                        \
    const int wm = (w >> 1) * 32, wn = (w & 1) * 64;                                 \
    const int srow4 = lane >> 2;                                                     \
    const int sc = (lane & 3) ^ (srow4 & 3);                                         \
    const u16* asrc  = A  + (size_t)(gm0 + w * 16 + srow4) * 512 + sc * 8;           \
    const u16* bsrc0 = BT + (size_t)(gn0 + w * 32 + srow4) * 512 + sc * 8;           \
    const u16* bsrc1 = BT + (size_t)(gn0 + w * 32 + 16 + srow4) * 512 + sc * 8;      \
    f32x4 acc[2][4] = {};                                                            \
    gload16(asrc, &As[0][w * 512]);                                                  \
    gload16(bsrc0, &Bs[0][w * 1024]);                                                \
    gload16(bsrc1, &Bs[0][w * 1024 + 512]);                                          \
    for (int kt = 0; kt < 16; ++kt) {                                                \
        const int cur = kt & 1;                                                      \
        if (kt < 15) {                                                               \
            gload16(asrc + (kt + 1) * 32, &As[cur ^ 1][w * 512]);                    \
            gload16(bsrc0 + (kt + 1) * 32, &Bs[cur ^ 1][w * 1024]);                  \
            gload16(bsrc1 + (kt + 1) * 32, &Bs[cur ^ 1][w * 1024 + 512]);            \
            asm volatile("s_waitcnt vmcnt(3)" ::: "memory");                         \
        } else {                                                                     \
            asm volatile("s_waitcnt vmcnt(0)" ::: "memory");                         \
        }                                                                            \
        __syncthreads();                                                             \
        short8 af[2], bfr[4];                                                        \
        _Pragma("unroll")                                                            \
        for (int i = 0; i < 2; ++i)                                                  \
            af[i] = *(const short8*)&As[cur][(wm + i * 16 + lr) * 32 + (lg ^ (lr & 3)) * 8]; \
        _Pragma("unroll")                                                            \
        for (int j = 0; j < 4; ++j)                                                  \
            bfr[j] = *(const short8*)&Bs[cur][(wn + j * 16 + lr) * 32 + (lg ^ (lr & 3)) * 8]; \
        _Pragma("unroll")                                                            \
        for (int i = 0; i < 2; ++i)                                                  \
            _Pragma("unroll")                                                        \
            for (int j = 0; j < 4; ++j)                                              \
                acc[i][j] = __builtin_amdgcn_mfma_f32_16x16x32_bf16(af[i], bfr[j], acc[i][j], 0, 0, 0); \
        __syncthreads();                                                             \
    }

// Q/K/V GEMMs: z = blockIdx.z + zbase selects branch. z==2 writes vbT layout.
// zbase split keeps the cbv->qbuf aliasing safe (V launch completes first).
__global__ __launch_bounds__(256) void gemm_qkv(
    const u16* __restrict__ Aq, const u16* __restrict__ Ak, const u16* __restrict__ Av,
    const u16* __restrict__ wTb, const float* __restrict__ bq,
    const float* __restrict__ bk, const float* __restrict__ bv,
    u16* __restrict__ qout, u16* __restrict__ kout, u16* __restrict__ vbT, int zbase) {
    __shared__ u16 As[2][64 * 32];
    __shared__ u16 Bs[2][128 * 32];
    const int z = blockIdx.z + zbase;
    const u16* A = z == 0 ? Aq : z == 1 ? Ak : Av;
    const u16* BT = wTb + (size_t)z * 262144;
    const float* bias = z == 0 ? bq : z == 1 ? bk : bv;
    GEMM_BODY(A, BT)
    u16* lin = z == 0 ? qout : kout;
#pragma unroll
    for (int i = 0; i < 2; ++i)
#pragma unroll
        for (int j = 0; j < 4; ++j) {
            const int gc = gn0 + wn + j * 16 + lr;
            const float bvl = bias[gc];
#pragma unroll
            for (int r = 0; r < 4; ++r) {
                const int gr = gm0 + wm + i * 16 + lg * 4 + r;
                const float val = acc[i][j][r] + bvl;
                if (z == 2) {
                    const int b2 = gr / NTOK, k = gr - b2 * NTOK;
                    const int hh = gc >> 6, d = gc & 63;
                    vbT[((size_t)(b2 * MH + hh) * 64 + d) * KPAD + k] = f2b(val);
                } else {
                    lin[(size_t)gr * 512 + gc] = f2b(val);
                }
            }
        }
}

// final projection GEMM: f32 out
__global__ __launch_bounds__(256) void gemm_out(const u16* __restrict__ Ain,
                                                const u16* __restrict__ BTin,
                                                const float* __restrict__ bias,
                                                float* __restrict__ C) {
    __shared__ u16 As[2][64 * 32];
    __shared__ u16 Bs[2][128 * 32];
    GEMM_BODY(Ain, BTin)
#pragma unroll
    for (int i = 0; i < 2; ++i)
#pragma unroll
        for (int j = 0; j < 4; ++j) {
            const int gc = gn0 + wn + j * 16 + lr;
            const float bvl = bias[gc];
#pragma unroll
            for (int r = 0; r < 4; ++r) {
                const int gr = gm0 + wm + i * 16 + lg * 4 + r;
                C[(size_t)gr * 512 + gc] = acc[i][j][r] + bvl;
            }
        }
}

// -------- bias tables, pre-scaled by log2(e) (softmax runs in exp2 domain) --------
__global__ __launch_bounds__(256) void build_bias_t(const float* __restrict__ rpb_t,
                                                    const float* __restrict__ tt,
                                                    const float* __restrict__ tg,
                                                    u16* __restrict__ btab) {
    const int q = blockIdx.x, h = blockIdx.y;
    const int qh = q / 22, qw = q % 22;
    const float tgv = tg[h * NTGT + q];
    for (int k = threadIdx.x; k < KPAD; k += 256) {
        float val;
        if (k < NTMP) val = (tt[h * NTMP + k] + tgv) * LOG2E;
        else if (k < NTOK) {
            const int kj = k - NTMP, kh = kj / 22, kw = kj % 22;
            val = rpb_t[((qh - kh + 21) * 43 + (qw - kw + 21)) * MH + h] * LOG2E;
        } else val = -1e30f;
        btab[((size_t)(h * NTGT + q)) * KPAD + k] = f2b(val);
    }
}
__global__ __launch_bounds__(256) void build_bias_m(const float* __restrict__ rpb_m,
                                                    u16* __restrict__ mtab) {
    const int q = blockIdx.x, k = threadIdx.x;
    const int qh = q >> 4, qw = q & 15, kh = k >> 4, kw = k & 15;
    mtab[q * 256 + k] = f2b(rpb_m[(qh - kh + 15) * 31 + (qw - kw + 15)] * LOG2E);
}

// ---------------- merged MFMA flash attention (O^T form, 32-key chunks) ----------------
// XCD-remapped grid; K/V staged via global_load_lds with pre-swizzled source.
__global__ __launch_bounds__(256) void attn_all(const u16* __restrict__ qb,
                                                const u16* __restrict__ kb,
                                                const u16* __restrict__ vbT,
                                                const u16* __restrict__ btab,
                                                const u16* __restrict__ mtab,
                                                u16* __restrict__ attb) {
    __shared__ u16 Ks[2][32][64];    // keys x d  (8-chunk swizzle, 128B rows)
    __shared__ u16 VTs[2][64][32];   // d x keys  (4-chunk swizzle incl. >>2 term)
    __shared__ u16 Pb[4][16][32];    // per-wave P^T round-trip (4-chunk swizzle)

    // XCD-bijective remap: 1536 blocks % 8 XCDs == 0. Each XCD gets 192
    // contiguous logical blocks = 16 (h,b) pairs x 12 q-tiles -> K/V L2-local.
    int wg = blockIdx.x + 12 * (blockIdx.y + 8 * blockIdx.z);
    wg = (wg & 7) * 192 + (wg >> 3);
    const int bx = wg % 12;
    const int hb = wg / 12;
    const int h = hb & 7, b = hb >> 3;

    const bool tgt = bx < 8;
    const int q0 = (tgt ? bx : bx - 8) * 64;
    const int NKr = tgt ? NTOK : NTMP;
    const int NCH = tgt ? 24 : 8;
    const int QTOT = tgt ? NTGT : NTMP;
    const int QOFF = tgt ? NTMP : 0;
    const int tid = threadIdx.x;
    const int w = tid >> 6, lane = tid & 63;
    const int lq = lane & 15, lg = lane >> 4;
    const int fq = (lq & 3) ^ ((lq >> 2) & 3);      // phase-safe 4-chunk swizzle
    const size_t brow = (size_t)b * NTOK;
    const float SCL = 0.125f * LOG2E;

    int qmine = q0 + w * 16 + lq;
    if (qmine > QTOT - 1) qmine = QTOT - 1;
    const u16* trow = tgt ? (btab + ((size_t)(h * NTGT + qmine)) * KPAD)
                          : (mtab + qmine * 256);

    short8 qf[2];
#pragma unroll
    for (int dc = 0; dc < 2; ++dc)
        qf[dc] = *(const short8*)(qb + (brow + QOFF + qmine) * DM + h * 64 + dc * 32 + lg * 8);

    // staging: gload_lds, lane-linear LDS dest; source chunk pre-XORed with row fn
    const int krow = tid >> 3, ksc = tid & 7;           // K: row=krow, pos=ksc
    const int vrow = tid >> 2, vsc = tid & 3;           // V: row=vrow, pos=vsc
    const int fv = (vrow & 3) ^ ((vrow >> 2) & 3);
    const size_t vbase = (size_t)(b * MH + h) * 64 * KPAD;
    const u16* kptr2 = kb + brow * DM + h * 64 + (ksc ^ (krow & 7)) * 8;
    const u16* vptr2 = vbT + vbase + (size_t)vrow * KPAD + (vsc ^ fv) * 8;
    const int NKm1 = NKr - 1;

    float mrun = -1e30f, lrun = 0.f;
    f32x4 oT[4] = {};

    // prologue: stage chunk 0 (async)
    {
        const int keyc = krow < NKm1 ? krow : NKm1;   // clamp: dup row, masked by -1e30 bias
        gload16(kptr2 + (size_t)keyc * DM, &Ks[0][w * 8][0]);
        gload16(vptr2, &VTs[0][w * 16][0]);
    }
    us4 bc0 = *(const us4*)(trow + lg * 4);
    us4 bc1 = *(const us4*)(trow + 16 + lg * 4);
    asm volatile("s_waitcnt vmcnt(0)" ::: "memory");
    __syncthreads();

    for (int kc = 0; kc < NCH; ++kc) {
        const int cur = kc & 1, nxt = cur ^ 1;
        const bool more = (kc + 1 < NCH);
        us4 bn0 = {0, 0, 0, 0}, bn1 = {0, 0, 0, 0};
        if (more) {
            const int key = (kc + 1) * 32 + krow;
            const int keyc = key < NKm1 ? key : NKm1;
            gload16(kptr2 + (size_t)keyc * DM, &Ks[nxt][w * 8][0]);
            gload16(vptr2 + (kc + 1) * 32, &VTs[nxt][w * 16][0]);
            bn0 = *(const us4*)(trow + (kc + 1) * 32 + lg * 4);
            bn1 = *(const us4*)(trow + (kc + 1) * 32 + 16 + lg * 4);
        }

        // ---- S^T: D[key][q] ----
        f32x4 s0 = {}, s1 = {};
        __builtin_amdgcn_s_setprio(1);
#pragma unroll
        for (int dc = 0; dc < 2; ++dc) {
            short8 a0 = *(const short8*)&Ks[cur][lq][((dc * 4 + lg) ^ (lq & 7)) * 8];
            short8 a1 = *(const short8*)&Ks[cur][16 + lq][((dc * 4 + lg) ^ (lq & 7)) * 8];
            s0 = __builtin_amdgcn_mfma_f32_16x16x32_bf16(a0, qf[dc], s0, 0, 0, 0);
            s1 = __builtin_amdgcn_mfma_f32_16x16x32_bf16(a1, qf[dc], s1, 0, 0, 0);
        }
        __builtin_amdgcn_s_setprio(0);
        float sv[8];
        sv[0] = fmaf(s0[0], SCL, b2f(bc0.x)); sv[1] = fmaf(s0[1], SCL, b2f(bc0.y));
        sv[2] = fmaf(s0[2], SCL, b2f(bc0.z)); sv[3] = fmaf(s0[3], SCL, b2f(bc0.w));
        sv[4] = fmaf(s1[0], SCL, b2f(bc1.x)); sv[5] = fmaf(s1[1], SCL, b2f(bc1.y));
        sv[6] = fmaf(s1[2], SCL, b2f(bc1.z)); sv[7] = fmaf(s1[3], SCL, b2f(bc1.w));

        // ---- online softmax in exp2 domain; stats lane-local per q ----
        float cm = sv[0];
#pragma unroll
        for (int i = 1; i < 8; ++i) cm = fmaxf(cm, sv[i]);
        cm = fmaxf(cm, __shfl_xor(cm, 16));
        cm = fmaxf(cm, __shfl_xor(cm, 32));
        if (!__all(cm <= mrun)) {                    // defer-max: exact skip
            const float mnew = fmaxf(mrun, cm);
            const float alpha = fexp2(mrun - mnew);
#pragma unroll
            for (int t = 0; t < 4; ++t)
#pragma unroll
                for (int r = 0; r < 4; ++r) oT[t][r] *= alpha;
            lrun *= alpha;
            mrun = mnew;
        }
        float pv[8]; float psum = 0.f;
#pragma unroll
        for (int i = 0; i < 8; ++i) { pv[i] = fexp2(sv[i] - mrun); psum += pv[i]; }

        const int c0 = (((lg >> 1) ^ fq) & 3) * 8 + (lg & 1) * 4;
        const int c1 = (((2 + (lg >> 1)) ^ fq) & 3) * 8 + (lg & 1) * 4;
        *(uint2*)&Pb[w][lq][c0] = uint2{pk2(pv[0], pv[1]), pk2(pv[2], pv[3])};
        *(uint2*)&Pb[w][lq][c1] = uint2{pk2(pv[4], pv[5]), pk2(pv[6], pv[7])};

        psum += __shfl_xor(psum, 16);
        psum += __shfl_xor(psum, 32);
        lrun += psum;

        asm volatile("s_waitcnt lgkmcnt(0)" ::: "memory");

        // ---- PV: O^T[d][q] += V^T[d][32k] * P^T[32k][q] ----
        short8 pf = *(const short8*)&Pb[w][lq][((lg ^ fq) & 3) * 8];
        __builtin_amdgcn_s_setprio(1);
#pragma unroll
        for (int t = 0; t < 4; ++t) {
            short8 vf = *(const short8*)&VTs[cur][t * 16 + lq][((lg ^ fq) & 3) * 8];
            oT[t] = __builtin_amdgcn_mfma_f32_16x16x32_bf16(vf, pf, oT[t], 0, 0, 0);
        }
        __builtin_amdgcn_s_setprio(0);

        bc0 = bn0; bc1 = bn1;
        asm volatile("s_waitcnt vmcnt(0)" ::: "memory");   // next-chunk gload_lds done
        __syncthreads();
    }

    // epilogue: O[q][d] store, q=lq lane-local, d = t*16+lg*4..+3
    const float linv = 1.f / lrun;
    const int qrow = q0 + w * 16 + lq;
    if (qrow < QTOT) {
        u16* op = attb + (brow + QOFF + qrow) * DM + h * 64;
#pragma unroll
        for (int t = 0; t < 4; ++t)
            *(uint2*)(op + t * 16 + lg * 4) =
                uint2{pk2(oT[t][0] * linv, oT[t][1] * linv),
                      pk2(oT[t][2] * linv, oT[t][3] * linv)};
    }
}

// ---------------- launch ----------------
extern "C" void kernel_launch(void* const* d_in, const int* in_sizes, int n_in,
                              void* d_out, int out_size, void* d_ws, size_t ws_size,
                              hipStream_t stream) {
    const float* x = (const float*)d_in[0];
    const float* convw[3] = {(const float*)d_in[1], (const float*)d_in[6], (const float*)d_in[11]};
    const float* bng[3]   = {(const float*)d_in[2], (const float*)d_in[7], (const float*)d_in[12]};
    const float* bnb[3]   = {(const float*)d_in[3], (const float*)d_in[8], (const float*)d_in[13]};
    const float* bnm[3]   = {(const float*)d_in[4], (const float*)d_in[9], (const float*)d_in[14]};
    const float* bnv[3]   = {(const float*)d_in[5], (const float*)d_in[10], (const float*)d_in[15]};
    const float* w[4]     = {(const float*)d_in[16], (const float*)d_in[18], (const float*)d_in[20], (const float*)d_in[22]};
    const float* bias[4]  = {(const float*)d_in[17], (const float*)d_in[19], (const float*)d_in[21], (const float*)d_in[23]};
    const float* rpb_t = (const float*)d_in[24];
    const float* rpb_m = (const float*)d_in[25];
    const float* tt    = (const float*)d_in[26];
    const float* tg    = (const float*)d_in[27];

    char* ws = (char*)d_ws;
    u16* wTb = (u16*)ws;                                               // 4 x 512KB
    const size_t SEQ = (size_t)MROWS * DM * 2;   // 12,124,160 B
    u16* cbq  = (u16*)(ws + 2097152);
    u16* cbk  = (u16*)(ws + 2097152 + SEQ);
    u16* cbv  = (u16*)(ws + 2097152 + 2 * SEQ);
    u16* kbuf = (u16*)(ws + 2097152 + 3 * SEQ);
    u16* vbT  = (u16*)(ws + 2097152 + 4 * SEQ);                       // 12,582,912
    u16* btab = (u16*)(ws + 2097152 + 4 * SEQ + 12582912);            // 5,947,392
    u16* mtab = (u16*)(ws + 2097152 + 4 * SEQ + 12582912 + 5947392);  // 131,072
    float* cwf = (float*)(ws + 2097152 + 4 * SEQ + 12582912 + 5947392 + 131072);
    float* shf = cwf + 3 * 9 * DM;
    u16* qbuf = cbv;   // cbv dead after V-GEMM launch (ordered before Q/K launch)
    u16* attb = cbq;   // cbq dead after Q-GEMM

    transpose4<<<dim3(16, 16, 4), dim3(32, 8), 0, stream>>>(w[0], w[1], w[2], w[3], wTb);
    prep_conv3<<<dim3(9, 3), 512, 0, stream>>>(
        convw[0], bng[0], bnb[0], bnm[0], bnv[0],
        convw[1], bng[1], bnb[1], bnm[1], bnv[1],
        convw[2], bng[2], bnb[2], bnm[2], bnv[2], cwf, shf);
    build_bias_t<<<dim3(NTGT, MH), 256, 0, stream>>>(rpb_t, tt, tg, btab);
    build_bias_m<<<256, 256, 0, stream>>>(rpb_m, mtab);

    conv_bn3<<<MROWS / 2, 256, 0, stream>>>(x, cwf, shf, cbq, cbk, cbv);

    // V first (reads cbv), then Q+K (Q writes qbuf==cbv) — stream order makes it safe
    gemm_qkv<<<dim3(185, 4, 1), 256, 0, stream>>>(cbq, cbk, cbv, wTb,
                                                  bias[0], bias[1], bias[2],
                                                  qbuf, kbuf, vbT, 2);
    gemm_qkv<<<dim3(185, 4, 2), 256, 0, stream>>>(cbq, cbk, cbv, wTb,
                                                  bias[0], bias[1], bias[2],
                                                  qbuf, kbuf, vbT, 0);

    attn_all<<<dim3(12, 8, 16), 256, 0, stream>>>(qbuf, kbuf, vbT, btab, mtab, attb);

    gemm_out<<<dim3(185, 4), 256, 0, stream>>>(attb, wTb + 3 * 262144, bias[3], (float*)d_out);
}

// Round 12
// 179.140 us; speedup vs baseline: 2.1269x; 1.0306x over previous
//
#include <hip/hip_runtime.h>
#include <hip/hip_bf16.h>

typedef unsigned short u16;
typedef unsigned int u32;
typedef __attribute__((ext_vector_type(8))) short short8;   // 8 bf16 (4 VGPRs)
typedef __attribute__((ext_vector_type(4))) float f32x4;

#define NTOK 740
#define NTMP 256
#define NTGT 484
#define DM   512
#define MH   8
#define MROWS 11840   // B*NTOK = 16*740
#define KPAD 768
#define LOG2E 1.4426950408889634f

__device__ __forceinline__ float b2f(u16 u) {
    union { unsigned int i; float f; } x; x.i = ((unsigned int)u) << 16; return x.f;
}
__device__ __forceinline__ u16 f2b(float f) {
    union { float f; unsigned int i; } x; x.f = f;
    unsigned int r = x.i + 0x7FFFu + ((x.i >> 16) & 1u);   // RNE
    return (u16)(r >> 16);
}
__device__ __forceinline__ u32 pk2(float a, float b) {
    union { __hip_bfloat162 h; u32 u; } p;
    p.h = __float22bfloat162_rn(float2{a, b});
    return p.u;
}
__device__ __forceinline__ float fexp2(float x) {   // raw v_exp_f32 (log2 domain)
    return __builtin_amdgcn_exp2f(x);
}
struct alignas(8) us4 { u16 x, y, z, w; };

__device__ __forceinline__ void gload16(const void* g, void* l) {
    __builtin_amdgcn_global_load_lds(
        (const __attribute__((address_space(1))) void*)g,
        (__attribute__((address_space(3))) void*)l, 16, 0, 0);
}

// -------- weight transpose + bf16 convert: WT[n][k] = W[k][n], all 4 weights --------
__global__ __launch_bounds__(256) void transpose4(const float* __restrict__ w0,
                                                  const float* __restrict__ w1,
                                                  const float* __restrict__ w2,
                                                  const float* __restrict__ w3,
                                                  u16* __restrict__ wTbase) {
    __shared__ float t[32][33];
    const int z = blockIdx.z;
    const float* W = z == 0 ? w0 : z == 1 ? w1 : z == 2 ? w2 : w3;
    u16* WT = wTbase + (size_t)z * 262144;
    int bx = blockIdx.x, by = blockIdx.y;
    int tx = threadIdx.x;
    for (int i = threadIdx.y; i < 32; i += 8)
        t[i][tx] = W[(size_t)(by * 32 + i) * 512 + bx * 32 + tx];
    __syncthreads();
    for (int i = threadIdx.y; i < 32; i += 8)
        WT[(size_t)(bx * 32 + i) * 512 + by * 32 + tx] = f2b(t[tx][i]);
}

// -------- conv weight prep (3 branches): cwf[tap][c] = cw[c][tap]*inv; shift --------
__global__ __launch_bounds__(512) void prep_conv3(
    const float* __restrict__ cw0, const float* __restrict__ g0, const float* __restrict__ bb0,
    const float* __restrict__ m0, const float* __restrict__ v0,
    const float* __restrict__ cw1, const float* __restrict__ g1, const float* __restrict__ bb1,
    const float* __restrict__ m1, const float* __restrict__ v1,
    const float* __restrict__ cw2, const float* __restrict__ g2, const float* __restrict__ bb2,
    const float* __restrict__ m2, const float* __restrict__ v2,
    float* __restrict__ cwfb, float* __restrict__ shb) {
    const int tap = blockIdx.x, br = blockIdx.y, c = threadIdx.x;
    const float* cw = br == 0 ? cw0 : br == 1 ? cw1 : cw2;
    const float* g  = br == 0 ? g0  : br == 1 ? g1  : g2;
    const float* bb = br == 0 ? bb0 : br == 1 ? bb1 : bb2;
    const float* m  = br == 0 ? m0  : br == 1 ? m1  : m2;
    const float* v  = br == 0 ? v0  : br == 1 ? v1  : v2;
    const float inv = g[c] * rsqrtf(v[c] + 1e-5f);
    cwfb[(br * 9 + tap) * DM + c] = cw[c * 9 + tap] * inv;
    if (tap == 0) shb[br * DM + c] = bb[c] - m[c] * inv;
}

// ---------------- fused depthwise 3x3 conv (+folded BN) for q,k,v ----------------
__global__ __launch_bounds__(256) void conv_bn3(
    const float* __restrict__ x,
    const float* __restrict__ cwfb, const float* __restrict__ shb,
    u16* __restrict__ o0, u16* __restrict__ o1, u16* __restrict__ o2) {
    const int bn = blockIdx.x * 2 + (threadIdx.x >> 7);
    const int c = (threadIdx.x & 127) * 4;
    const int b = bn / NTOK, n = bn % NTOK;
    const bool tmp = n < NTMP;
    const int L = tmp ? 16 : 22, base = tmp ? 0 : NTMP, p = n - base;
    const int ph = p / L, pw = p % L;
    float4 xv[9];
#pragma unroll
    for (int tap = 0; tap < 9; ++tap) {
        const int dh = tap / 3 - 1, dw = tap % 3 - 1;
        const int h2 = ph + dh, w2 = pw + dw;
        const bool ok = (h2 >= 0 && h2 < L && w2 >= 0 && w2 < L);
        xv[tap] = ok ? *(const float4*)(x + (size_t)(b * NTOK + base + h2 * L + w2) * DM + c)
                     : float4{0.f, 0.f, 0.f, 0.f};
    }
    const size_t o = (size_t)bn * DM + c;
    u16* out[3] = {o0, o1, o2};
#pragma unroll
    for (int br = 0; br < 3; ++br) {
        float4 acc = *(const float4*)(shb + br * DM + c);
#pragma unroll
        for (int tap = 0; tap < 9; ++tap) {
            const float4 wv = *(const float4*)(cwfb + (br * 9 + tap) * DM + c);
            acc.x = fmaf(wv.x, xv[tap].x, acc.x);
            acc.y = fmaf(wv.y, xv[tap].y, acc.y);
            acc.z = fmaf(wv.z, xv[tap].z, acc.z);
            acc.w = fmaf(wv.w, xv[tap].w, acc.w);
        }
        us4 r;
        r.x = f2b(acc.x); r.y = f2b(acc.y); r.z = f2b(acc.z); r.w = f2b(acc.w);
        *(us4*)(out[br] + o) = r;
    }
}

// ---------------- shared GEMM body macro (64x128 tile, global_load_lds) ----------------
#define GEMM_BODY(A, BT)                                                             \
    const int tid = threadIdx.x;                                                     \
    const int gm0 = blockIdx.x * 64;                                                 \
    const int gn0 = blockIdx.y * 128;                                                \
    const int lane = tid & 63, w = tid >> 6;                                         \
    const int lr = lane & 15, lg = lane >> 4;                                        \
    const int wm = (w >> 1) * 32, wn = (w & 1) * 64;                                 \
    const int srow4 = lane >> 2;                                                     \
    const int sc = (lane & 3) ^ (srow4 & 3);                                         \
    const u16* asrc  = A  + (size_t)(gm0 + w * 16 + srow4) * 512 + sc * 8;           \
    const u16* bsrc0 = BT + (size_t)(gn0 + w * 32 + srow4) * 512 + sc * 8;           \
    const u16* bsrc1 = BT + (size_t)(gn0 + w * 32 + 16 + srow4) * 512 + sc * 8;      \
    f32x4 acc[2][4] = {};                                                            \
    gload16(asrc, &As[0][w * 512]);                                                  \
    gload16(bsrc0, &Bs[0][w * 1024]);                                                \
    gload16(bsrc1, &Bs[0][w * 1024 + 512]);                                          \
    for (int kt = 0; kt < 16; ++kt) {                                                \
        const int cur = kt & 1;                                                      \
        if (kt < 15) {                                                               \
            gload16(asrc + (kt + 1) * 32, &As[cur ^ 1][w * 512]);                    \
            gload16(bsrc0 + (kt + 1) * 32, &Bs[cur ^ 1][w * 1024]);                  \
            gload16(bsrc1 + (kt + 1) * 32, &Bs[cur ^ 1][w * 1024 + 512]);            \
            asm volatile("s_waitcnt vmcnt(3)" ::: "memory");                         \
        } else {                                                                     \
            asm volatile("s_waitcnt vmcnt(0)" ::: "memory");                         \
        }                                                                            \
        __syncthreads();                                                             \
        short8 af[2], bfr[4];                                                        \
        _Pragma("unroll")                                                            \
        for (int i = 0; i < 2; ++i)                                                  \
            af[i] = *(const short8*)&As[cur][(wm + i * 16 + lr) * 32 + (lg ^ (lr & 3)) * 8]; \
        _Pragma("unroll")                                                            \
        for (int j = 0; j < 4; ++j)                                                  \
            bfr[j] = *(const short8*)&Bs[cur][(wn + j * 16 + lr) * 32 + (lg ^ (lr & 3)) * 8]; \
        _Pragma("unroll")                                                            \
        for (int i = 0; i < 2; ++i)                                                  \
            _Pragma("unroll")                                                        \
            for (int j = 0; j < 4; ++j)                                              \
                acc[i][j] = __builtin_amdgcn_mfma_f32_16x16x32_bf16(af[i], bfr[j], acc[i][j], 0, 0, 0); \
        __syncthreads();                                                             \
    }

// Q/K/V GEMMs: z = blockIdx.z + zbase selects branch. z==2 writes vbT layout.
__global__ __launch_bounds__(256) void gemm_qkv(
    const u16* __restrict__ Aq, const u16* __restrict__ Ak, const u16* __restrict__ Av,
    const u16* __restrict__ wTb, const float* __restrict__ bq,
    const float* __restrict__ bk, const float* __restrict__ bv,
    u16* __restrict__ qout, u16* __restrict__ kout, u16* __restrict__ vbT, int zbase) {
    __shared__ u16 As[2][64 * 32];
    __shared__ u16 Bs[2][128 * 32];
    const int z = blockIdx.z + zbase;
    const u16* A = z == 0 ? Aq : z == 1 ? Ak : Av;
    const u16* BT = wTb + (size_t)z * 262144;
    const float* bias = z == 0 ? bq : z == 1 ? bk : bv;
    GEMM_BODY(A, BT)
    u16* lin = z == 0 ? qout : kout;
#pragma unroll
    for (int i = 0; i < 2; ++i)
#pragma unroll
        for (int j = 0; j < 4; ++j) {
            const int gc = gn0 + wn + j * 16 + lr;
            const float bvl = bias[gc];
#pragma unroll
            for (int r = 0; r < 4; ++r) {
                const int gr = gm0 + wm + i * 16 + lg * 4 + r;
                const float val = acc[i][j][r] + bvl;
                if (z == 2) {
                    const int b2 = gr / NTOK, k = gr - b2 * NTOK;
                    const int hh = gc >> 6, d = gc & 63;
                    vbT[((size_t)(b2 * MH + hh) * 64 + d) * KPAD + k] = f2b(val);
                } else {
                    lin[(size_t)gr * 512 + gc] = f2b(val);
                }
            }
        }
}

// final projection GEMM: f32 out
__global__ __launch_bounds__(256) void gemm_out(const u16* __restrict__ Ain,
                                                const u16* __restrict__ BTin,
                                                const float* __restrict__ bias,
                                                float* __restrict__ C) {
    __shared__ u16 As[2][64 * 32];
    __shared__ u16 Bs[2][128 * 32];
    GEMM_BODY(Ain, BTin)
#pragma unroll
    for (int i = 0; i < 2; ++i)
#pragma unroll
        for (int j = 0; j < 4; ++j) {
            const int gc = gn0 + wn + j * 16 + lr;
            const float bvl = bias[gc];
#pragma unroll
            for (int r = 0; r < 4; ++r) {
                const int gr = gm0 + wm + i * 16 + lg * 4 + r;
                C[(size_t)gr * 512 + gc] = acc[i][j][r] + bvl;
            }
        }
}

// -------- bias tables, pre-scaled by log2(e) (softmax runs in exp2 domain) --------
__global__ __launch_bounds__(256) void build_bias_t(const float* __restrict__ rpb_t,
                                                    const float* __restrict__ tt,
                                                    const float* __restrict__ tg,
                                                    u16* __restrict__ btab) {
    const int q = blockIdx.x, h = blockIdx.y;
    const int qh = q / 22, qw = q % 22;
    const float tgv = tg[h * NTGT + q];
    for (int k = threadIdx.x; k < KPAD; k += 256) {
        float val;
        if (k < NTMP) val = (tt[h * NTMP + k] + tgv) * LOG2E;
        else if (k < NTOK) {
            const int kj = k - NTMP, kh = kj / 22, kw = kj % 22;
            val = rpb_t[((qh - kh + 21) * 43 + (qw - kw + 21)) * MH + h] * LOG2E;
        } else val = -1e30f;
        btab[((size_t)(h * NTGT + q)) * KPAD + k] = f2b(val);
    }
}
__global__ __launch_bounds__(256) void build_bias_m(const float* __restrict__ rpb_m,
                                                    u16* __restrict__ mtab) {
    const int q = blockIdx.x, k = threadIdx.x;
    const int qh = q >> 4, qw = q & 15, kh = k >> 4, kw = k & 15;
    mtab[q * 256 + k] = f2b(rpb_m[(qh - kh + 15) * 31 + (qw - kw + 15)] * LOG2E);
}

// ---------------- merged MFMA flash attention: 128 q-rows/block, O^T form ----------------
// grid.x: 0..3 target 128-q tiles, 4..5 temp. K/V LDS chunks shared by two q-tiles.
__global__ __launch_bounds__(256) void attn_all(const u16* __restrict__ qb,
                                                const u16* __restrict__ kb,
                                                const u16* __restrict__ vbT,
                                                const u16* __restrict__ btab,
                                                const u16* __restrict__ mtab,
                                                u16* __restrict__ attb) {
    __shared__ u16 Ks[2][32][64];       // keys x d  (8-chunk swizzle, 128B rows)
    __shared__ u16 VTs[2][64][32];      // d x keys  (4-chunk swizzle incl. >>2 term)
    __shared__ u16 Pb[2][4][16][32];    // per-(qtile,wave) P^T round-trip

    // XCD-bijective remap: 768 blocks % 8 == 0; 96/XCD = 16 (h,b) pairs x 6 tiles
    int wg = blockIdx.x + 6 * (blockIdx.y + 8 * blockIdx.z);
    wg = (wg & 7) * 96 + (wg >> 3);
    const int bx = wg % 6;
    const int hb = wg / 6;
    const int h = hb & 7, b = hb >> 3;

    const bool tgt = bx < 4;
    const int q0 = (tgt ? bx : bx - 4) * 128;
    const int NKr = tgt ? NTOK : NTMP;
    const int NCH = tgt ? 24 : 8;
    const int QTOT = tgt ? NTGT : NTMP;
    const int QOFF = tgt ? NTMP : 0;
    const int TK = tgt ? KPAD : 256;
    const int tid = threadIdx.x;
    const int w = tid >> 6, lane = tid & 63;
    const int lq = lane & 15, lg = lane >> 4;
    const int fq = (lq & 3) ^ ((lq >> 2) & 3);      // phase-safe 4-chunk swizzle
    const size_t brow = (size_t)b * NTOK;
    const float SCL = 0.125f * LOG2E;

    int qA = q0 + w * 16 + lq;       if (qA > QTOT - 1) qA = QTOT - 1;
    int qB = q0 + 64 + w * 16 + lq;  if (qB > QTOT - 1) qB = QTOT - 1;
    const u16* tbase = tgt ? (btab + (size_t)h * NTGT * KPAD) : mtab;
    const u16* trowA = tbase + (size_t)qA * TK;
    const u16* trowB = tbase + (size_t)qB * TK;

    short8 qfA[2], qfB[2];
#pragma unroll
    for (int dc = 0; dc < 2; ++dc) {
        qfA[dc] = *(const short8*)(qb + (brow + QOFF + qA) * DM + h * 64 + dc * 32 + lg * 8);
        qfB[dc] = *(const short8*)(qb + (brow + QOFF + qB) * DM + h * 64 + dc * 32 + lg * 8);
    }

    // staging: gload_lds, lane-linear LDS dest; source chunk pre-XORed with row fn
    const int krow = tid >> 3, ksc = tid & 7;
    const int vrow = tid >> 2, vsc = tid & 3;
    const int fv = (vrow & 3) ^ ((vrow >> 2) & 3);
    const size_t vbase = (size_t)(b * MH + h) * 64 * KPAD;
    const u16* kptr2 = kb + brow * DM + h * 64 + (ksc ^ (krow & 7)) * 8;
    const u16* vptr2 = vbT + vbase + (size_t)vrow * KPAD + (vsc ^ fv) * 8;
    const int NKm1 = NKr - 1;

    float mrunA = -1e30f, lrunA = 0.f, mrunB = -1e30f, lrunB = 0.f;
    f32x4 oTA[4] = {}, oTB[4] = {};

    {   // prologue: stage chunk 0 (async)
        const int keyc = krow < NKm1 ? krow : NKm1;
        gload16(kptr2 + (size_t)keyc * DM, &Ks[0][w * 8][0]);
        gload16(vptr2, &VTs[0][w * 16][0]);
    }
    us4 bcA0 = *(const us4*)(trowA + lg * 4);
    us4 bcA1 = *(const us4*)(trowA + 16 + lg * 4);
    us4 bcB0 = *(const us4*)(trowB + lg * 4);
    us4 bcB1 = *(const us4*)(trowB + 16 + lg * 4);
    asm volatile("s_waitcnt vmcnt(0)" ::: "memory");
    __syncthreads();

    for (int kc = 0; kc < NCH; ++kc) {
        const int cur = kc & 1, nxt = cur ^ 1;
        const bool more = (kc + 1 < NCH);
        us4 bnA0 = {0,0,0,0}, bnA1 = {0,0,0,0}, bnB0 = {0,0,0,0}, bnB1 = {0,0,0,0};
        if (more) {
            const int key = (kc + 1) * 32 + krow;
            const int keyc = key < NKm1 ? key : NKm1;
            gload16(kptr2 + (size_t)keyc * DM, &Ks[nxt][w * 8][0]);
            gload16(vptr2 + (kc + 1) * 32, &VTs[nxt][w * 16][0]);
            bnA0 = *(const us4*)(trowA + (kc + 1) * 32 + lg * 4);
            bnA1 = *(const us4*)(trowA + (kc + 1) * 32 + 16 + lg * 4);
            bnB0 = *(const us4*)(trowB + (kc + 1) * 32 + lg * 4);
            bnB1 = *(const us4*)(trowB + (kc + 1) * 32 + 16 + lg * 4);
        }

        // ---- S^T for both q-tiles: K-frags read once ----
        f32x4 sA0 = {}, sA1 = {}, sB0 = {}, sB1 = {};
        __builtin_amdgcn_s_setprio(1);
#pragma unroll
        for (int dc = 0; dc < 2; ++dc) {
            short8 a0 = *(const short8*)&Ks[cur][lq][((dc * 4 + lg) ^ (lq & 7)) * 8];
            short8 a1 = *(const short8*)&Ks[cur][16 + lq][((dc * 4 + lg) ^ (lq & 7)) * 8];
            sA0 = __builtin_amdgcn_mfma_f32_16x16x32_bf16(a0, qfA[dc], sA0, 0, 0, 0);
            sB0 = __builtin_amdgcn_mfma_f32_16x16x32_bf16(a0, qfB[dc], sB0, 0, 0, 0);
            sA1 = __builtin_amdgcn_mfma_f32_16x16x32_bf16(a1, qfA[dc], sA1, 0, 0, 0);
            sB1 = __builtin_amdgcn_mfma_f32_16x16x32_bf16(a1, qfB[dc], sB1, 0, 0, 0);
        }
        __builtin_amdgcn_s_setprio(0);

        // ---- softmax tile A ----
        {
            float sv[8];
            sv[0] = fmaf(sA0[0], SCL, b2f(bcA0.x)); sv[1] = fmaf(sA0[1], SCL, b2f(bcA0.y));
            sv[2] = fmaf(sA0[2], SCL, b2f(bcA0.z)); sv[3] = fmaf(sA0[3], SCL, b2f(bcA0.w));
            sv[4] = fmaf(sA1[0], SCL, b2f(bcA1.x)); sv[5] = fmaf(sA1[1], SCL, b2f(bcA1.y));
            sv[6] = fmaf(sA1[2], SCL, b2f(bcA1.z)); sv[7] = fmaf(sA1[3], SCL, b2f(bcA1.w));
            float cm = sv[0];
#pragma unroll
            for (int i = 1; i < 8; ++i) cm = fmaxf(cm, sv[i]);
            cm = fmaxf(cm, __shfl_xor(cm, 16));
            cm = fmaxf(cm, __shfl_xor(cm, 32));
            if (!__all(cm <= mrunA)) {
                const float mnew = fmaxf(mrunA, cm);
                const float alpha = fexp2(mrunA - mnew);
#pragma unroll
                for (int t = 0; t < 4; ++t)
#pragma unroll
                    for (int r = 0; r < 4; ++r) oTA[t][r] *= alpha;
                lrunA *= alpha;
                mrunA = mnew;
            }
            float pv[8], psum = 0.f;
#pragma unroll
            for (int i = 0; i < 8; ++i) { pv[i] = fexp2(sv[i] - mrunA); psum += pv[i]; }
            const int c0 = (((lg >> 1) ^ fq) & 3) * 8 + (lg & 1) * 4;
            const int c1 = (((2 + (lg >> 1)) ^ fq) & 3) * 8 + (lg & 1) * 4;
            *(uint2*)&Pb[0][w][lq][c0] = uint2{pk2(pv[0], pv[1]), pk2(pv[2], pv[3])};
            *(uint2*)&Pb[0][w][lq][c1] = uint2{pk2(pv[4], pv[5]), pk2(pv[6], pv[7])};
            psum += __shfl_xor(psum, 16);
            psum += __shfl_xor(psum, 32);
            lrunA += psum;
        }
        // ---- softmax tile B ----
        {
            float sv[8];
            sv[0] = fmaf(sB0[0], SCL, b2f(bcB0.x)); sv[1] = fmaf(sB0[1], SCL, b2f(bcB0.y));
            sv[2] = fmaf(sB0[2], SCL, b2f(bcB0.z)); sv[3] = fmaf(sB0[3], SCL, b2f(bcB0.w));
            sv[4] = fmaf(sB1[0], SCL, b2f(bcB1.x)); sv[5] = fmaf(sB1[1], SCL, b2f(bcB1.y));
            sv[6] = fmaf(sB1[2], SCL, b2f(bcB1.z)); sv[7] = fmaf(sB1[3], SCL, b2f(bcB1.w));
            float cm = sv[0];
#pragma unroll
            for (int i = 1; i < 8; ++i) cm = fmaxf(cm, sv[i]);
            cm = fmaxf(cm, __shfl_xor(cm, 16));
            cm = fmaxf(cm, __shfl_xor(cm, 32));
            if (!__all(cm <= mrunB)) {
                const float mnew = fmaxf(mrunB, cm);
                const float alpha = fexp2(mrunB - mnew);
#pragma unroll
                for (int t = 0; t < 4; ++t)
#pragma unroll
                    for (int r = 0; r < 4; ++r) oTB[t][r] *= alpha;
                lrunB *= alpha;
                mrunB = mnew;
            }
            float pv[8], psum = 0.f;
#pragma unroll
            for (int i = 0; i < 8; ++i) { pv[i] = fexp2(sv[i] - mrunB); psum += pv[i]; }
            const int c0 = (((lg >> 1) ^ fq) & 3) * 8 + (lg & 1) * 4;
            const int c1 = (((2 + (lg >> 1)) ^ fq) & 3) * 8 + (lg & 1) * 4;
            *(uint2*)&Pb[1][w][lq][c0] = uint2{pk2(pv[0], pv[1]), pk2(pv[2], pv[3])};
            *(uint2*)&Pb[1][w][lq][c1] = uint2{pk2(pv[4], pv[5]), pk2(pv[6], pv[7])};
            psum += __shfl_xor(psum, 16);
            psum += __shfl_xor(psum, 32);
            lrunB += psum;
        }

        asm volatile("s_waitcnt lgkmcnt(0)" ::: "memory");

        // ---- PV both tiles: V-frags read once ----
        short8 pfA = *(const short8*)&Pb[0][w][lq][((lg ^ fq) & 3) * 8];
        short8 pfB = *(const short8*)&Pb[1][w][lq][((lg ^ fq) & 3) * 8];
        __builtin_amdgcn_s_setprio(1);
#pragma unroll
        for (int t = 0; t < 4; ++t) {
            short8 vf = *(const short8*)&VTs[cur][t * 16 + lq][((lg ^ fq) & 3) * 8];
            oTA[t] = __builtin_amdgcn_mfma_f32_16x16x32_bf16(vf, pfA, oTA[t], 0, 0, 0);
            oTB[t] = __builtin_amdgcn_mfma_f32_16x16x32_bf16(vf, pfB, oTB[t], 0, 0, 0);
        }
        __builtin_amdgcn_s_setprio(0);

        bcA0 = bnA0; bcA1 = bnA1; bcB0 = bnB0; bcB1 = bnB1;
        asm volatile("s_waitcnt vmcnt(0)" ::: "memory");
        __syncthreads();
    }

    // epilogue: O[q][d] stores, q lane-local
    {
        const float linv = 1.f / lrunA;
        const int qrow = q0 + w * 16 + lq;
        if (qrow < QTOT) {
            u16* op = attb + (brow + QOFF + qrow) * DM + h * 64;
#pragma unroll
            for (int t = 0; t < 4; ++t)
                *(uint2*)(op + t * 16 + lg * 4) =
                    uint2{pk2(oTA[t][0] * linv, oTA[t][1] * linv),
                          pk2(oTA[t][2] * linv, oTA[t][3] * linv)};
        }
    }
    {
        const float linv = 1.f / lrunB;
        const int qrow = q0 + 64 + w * 16 + lq;
        if (qrow < QTOT) {
            u16* op = attb + (brow + QOFF + qrow) * DM + h * 64;
#pragma unroll
            for (int t = 0; t < 4; ++t)
                *(uint2*)(op + t * 16 + lg * 4) =
                    uint2{pk2(oTB[t][0] * linv, oTB[t][1] * linv),
                          pk2(oTB[t][2] * linv, oTB[t][3] * linv)};
        }
    }
}

// ---------------- launch ----------------
extern "C" void kernel_launch(void* const* d_in, const int* in_sizes, int n_in,
                              void* d_out, int out_size, void* d_ws, size_t ws_size,
                              hipStream_t stream) {
    const float* x = (const float*)d_in[0];
    const float* convw[3] = {(const float*)d_in[1], (const float*)d_in[6], (const float*)d_in[11]};
    const float* bng[3]   = {(const float*)d_in[2], (const float*)d_in[7], (const float*)d_in[12]};
    const float* bnb[3]   = {(const float*)d_in[3], (const float*)d_in[8], (const float*)d_in[13]};
    const float* bnm[3]   = {(const float*)d_in[4], (const float*)d_in[9], (const float*)d_in[14]};
    const float* bnv[3]   = {(const float*)d_in[5], (const float*)d_in[10], (const float*)d_in[15]};
    const float* w[4]     = {(const float*)d_in[16], (const float*)d_in[18], (const float*)d_in[20], (const float*)d_in[22]};
    const float* bias[4]  = {(const float*)d_in[17], (const float*)d_in[19], (const float*)d_in[21], (const float*)d_in[23]};
    const float* rpb_t = (const float*)d_in[24];
    const float* rpb_m = (const float*)d_in[25];
    const float* tt    = (const float*)d_in[26];
    const float* tg    = (const float*)d_in[27];

    char* ws = (char*)d_ws;
    u16* wTb = (u16*)ws;                                               // 4 x 512KB
    const size_t SEQ = (size_t)MROWS * DM * 2;   // 12,124,160 B
    u16* cbq  = (u16*)(ws + 2097152);
    u16* cbk  = (u16*)(ws + 2097152 + SEQ);
    u16* cbv  = (u16*)(ws + 2097152 + 2 * SEQ);
    u16* kbuf = (u16*)(ws + 2097152 + 3 * SEQ);
    u16* vbT  = (u16*)(ws + 2097152 + 4 * SEQ);                       // 12,582,912
    u16* btab = (u16*)(ws + 2097152 + 4 * SEQ + 12582912);            // 5,947,392
    u16* mtab = (u16*)(ws + 2097152 + 4 * SEQ + 12582912 + 5947392);  // 131,072
    float* cwf = (float*)(ws + 2097152 + 4 * SEQ + 12582912 + 5947392 + 131072);
    float* shf = cwf + 3 * 9 * DM;                                    // ends +61,440
    const size_t off_q2 = 2097152 + 4 * SEQ + 12582912 + 5947392 + 131072 + 61440;
    const bool merged = ws_size >= off_q2 + SEQ;
    u16* qbuf = merged ? (u16*)(ws + off_q2) : cbv;   // fallback aliases cbv
    u16* attb = cbq;   // cbq dead after Q-GEMM

    transpose4<<<dim3(16, 16, 4), dim3(32, 8), 0, stream>>>(w[0], w[1], w[2], w[3], wTb);
    prep_conv3<<<dim3(9, 3), 512, 0, stream>>>(
        convw[0], bng[0], bnb[0], bnm[0], bnv[0],
        convw[1], bng[1], bnb[1], bnm[1], bnv[1],
        convw[2], bng[2], bnb[2], bnm[2], bnv[2], cwf, shf);
    build_bias_t<<<dim3(NTGT, MH), 256, 0, stream>>>(rpb_t, tt, tg, btab);
    build_bias_m<<<256, 256, 0, stream>>>(rpb_m, mtab);

    conv_bn3<<<MROWS / 2, 256, 0, stream>>>(x, cwf, shf, cbq, cbk, cbv);

    if (merged) {
        gemm_qkv<<<dim3(185, 4, 3), 256, 0, stream>>>(cbq, cbk, cbv, wTb,
                                                      bias[0], bias[1], bias[2],
                                                      qbuf, kbuf, vbT, 0);
    } else {
        // V first (reads cbv), then Q+K (Q writes qbuf==cbv) — stream order keeps it safe
        gemm_qkv<<<dim3(185, 4, 1), 256, 0, stream>>>(cbq, cbk, cbv, wTb,
                                                      bias[0], bias[1], bias[2],
                                                      qbuf, kbuf, vbT, 2);
        gemm_qkv<<<dim3(185, 4, 2), 256, 0, stream>>>(cbq, cbk, cbv, wTb,
                                                      bias[0], bias[1], bias[2],
                                                      qbuf, kbuf, vbT, 0);
    }

    attn_all<<<dim3(6, 8, 16), 256, 0, stream>>>(qbuf, kbuf, vbT, btab, mtab, attb);

    gemm_out<<<dim3(185, 4), 256, 0, stream>>>(attb, wTb + 3 * 262144, bias[3], (float*)d_out);
}